// Round 3
// baseline (102.766 us; speedup 1.0000x reference)
//
#include <hip/hip_runtime.h>

#define BB 4
#define TT 512
#define HH 512
#define UU 256

// 2*log2(e): e^{2x} = 2^{c*x}
#define C2L2E 2.8853900817779268f
#define L2E   1.4426950408889634f

typedef __attribute__((ext_vector_type(8))) short bf16x8;
typedef __attribute__((ext_vector_type(4))) float f32x4;

static __device__ inline unsigned short f2bf(float x) {
    union { float f; unsigned u; } v; v.f = x;
    unsigned r = v.u + 0x7fff + ((v.u >> 16) & 1);   // RNE
    return (unsigned short)(r >> 16);
}

// ---------------- prep: w2/scal/cbq, zero denom/wsum/out, h->bf16, WcatT ----------------
__global__ __launch_bounds__(256) void prep_kernel(const float* __restrict__ h,
                                                   const float* __restrict__ Wq,
                                                   const float* __restrict__ Wk,
                                                   const float* __restrict__ bq,
                                                   const float* __restrict__ W,
                                                   const float* __restrict__ b_alpha,
                                                   unsigned short* __restrict__ hbf,
                                                   unsigned short* __restrict__ WcatT,
                                                   float* __restrict__ cbq,
                                                   float* __restrict__ w2,
                                                   float* __restrict__ scal,
                                                   float* __restrict__ denom,
                                                   float* __restrict__ wsum,
                                                   float* __restrict__ out)
{
    const int tid = threadIdx.x;
    const int gid = blockIdx.x * 256 + tid;
    const int nthr = gridDim.x * 256;

    if (blockIdx.x == 0) {
        __shared__ float red[256];
        const float w = W[tid];
        w2[tid] = -2.0f * w;
        red[tid] = w;
        cbq[tid] = C2L2E * bq[tid];
        __syncthreads();
        for (int off = 128; off > 0; off >>= 1) {
            if (tid < off) red[tid] += red[tid + off];
            __syncthreads();
        }
        if (tid == 0) { scal[0] = red[0]; scal[1] = b_alpha[0]; }
    }

    for (int i = gid; i < BB * TT; i += nthr) {
        denom[i] = 0.0f; wsum[i] = 0.0f; out[i] = 0.0f;
    }
    for (int i = gid; i < BB * TT * HH; i += nthr) {
        hbf[i] = f2bf(h[i]);
    }
    // WcatT[n][k] = bf16(c * W{q,k}[k][n]), n in [0,512), k in [0,512)
    for (int i = gid; i < 512 * 512; i += nthr) {
        const int n = i & 511, k = i >> 9;
        const float v = (n < 256) ? Wq[k * UU + n] : Wk[k * UU + (n - 256)];
        WcatT[(size_t)n * 512 + k] = f2bf(C2L2E * v);
    }
}

// ---------------- kernel 1: bf16 MFMA GEMM, M=2048 N=512 K=512 ----------------
// n<256 -> c*hq, stored TRANSPOSED+quad-interleaved: CQ[(u>>2)*8192 + m*4 + (u&3)]
// n>=256 -> c*hk + c*bq, stored row-major: Ck[m*256 + (n-256)]
__global__ __launch_bounds__(256) void qk_mfma(const unsigned short* __restrict__ hbf,
                                               const unsigned short* __restrict__ WcatT,
                                               const float* __restrict__ cbq,
                                               float* __restrict__ CQ,
                                               float* __restrict__ Ck)
{
    const int wave = (blockIdx.x * 256 + threadIdx.x) >> 6;   // 0..2047
    const int lane = threadIdx.x & 63;
    const int mt = wave >> 4;          // 0..127
    const int nt = wave & 15;          // 0..15
    const int m0 = mt * 16, n0 = nt * 32;
    const int lrow = lane & 15;
    const int kgrp = lane >> 4;        // 0..3

    f32x4 acc0 = {0.f, 0.f, 0.f, 0.f};
    f32x4 acc1 = {0.f, 0.f, 0.f, 0.f};
    const unsigned short* Arow = hbf   + (size_t)(m0 + lrow) * 512 + kgrp * 8;
    const unsigned short* B0   = WcatT + (size_t)(n0 + lrow) * 512 + kgrp * 8;
    const unsigned short* B1   = B0 + (size_t)16 * 512;

#pragma unroll
    for (int k0 = 0; k0 < 512; k0 += 32) {
        const bf16x8 a  = *(const bf16x8*)(Arow + k0);
        const bf16x8 b0 = *(const bf16x8*)(B0 + k0);
        const bf16x8 b1 = *(const bf16x8*)(B1 + k0);
        acc0 = __builtin_amdgcn_mfma_f32_16x16x32_bf16(a, b0, acc0, 0, 0, 0);
        acc1 = __builtin_amdgcn_mfma_f32_16x16x32_bf16(a, b1, acc1, 0, 0, 0);
    }

    const int n_0 = n0 + lrow;
    const int n_1 = n_0 + 16;
    if (nt < 8) {
        // q-half: transposed quad-interleaved, no bias
#pragma unroll
        for (int r = 0; r < 4; r++) {
            const int m = m0 + kgrp * 4 + r;
            CQ[(size_t)(n_0 >> 2) * 8192 + m * 4 + (n_0 & 3)] = acc0[r];
            CQ[(size_t)(n_1 >> 2) * 8192 + m * 4 + (n_1 & 3)] = acc1[r];
        }
    } else {
        const float bias0 = cbq[n_0 - 256];
        const float bias1 = cbq[n_1 - 256];
#pragma unroll
        for (int r = 0; r < 4; r++) {
            const int m = m0 + kgrp * 4 + r;
            Ck[(size_t)m * 256 + (n_0 - 256)] = acc0[r] + bias0;
            Ck[(size_t)m * 256 + (n_1 - 256)] = acc1[r] + bias1;
        }
    }
}

// ---------------- kernel 2a: scores + sigmoid + exp, per-(b,t) denom ----------------
// grid (sg=32, tg=8, b=4), block 256 (4 waves). lane = t (coalesced CQ); wave owns 4 s.
__global__ __launch_bounds__(256) void score_kernel(const float* __restrict__ CQ,
                                                    const float* __restrict__ Ck,
                                                    const float* __restrict__ w2,
                                                    const float* __restrict__ scal,
                                                    float* __restrict__ E,
                                                    float* __restrict__ denom)
{
    const int b  = blockIdx.z;
    const int tg = blockIdx.y;
    const int sg = blockIdx.x;
    const int lane = threadIdx.x & 63;
    const int wv = __builtin_amdgcn_readfirstlane((int)(threadIdx.x >> 6));
    const int g  = b * TT + tg * 64 + lane;    // global row (b,t)
    const int s0 = sg * 16 + wv * 4;

    const float sumW    = scal[0];
    const float b_alpha = scal[1];

    float acc[4] = {0.f, 0.f, 0.f, 0.f};

    for (int uc = 0; uc < UU; uc += 32) {
        float4 hr[8];
#pragma unroll
        for (int q = 0; q < 8; q++)
            hr[q] = *(const float4*)(CQ + (size_t)(uc / 4 + q) * 8192 + g * 4);
        const float* __restrict__ w2c = w2 + uc;
#pragma unroll
        for (int si = 0; si < 4; ++si) {
            const float* __restrict__ hkr = Ck + (size_t)(b * TT + s0 + si) * UU + uc;
#pragma unroll
            for (int u = 0; u < 32; ++u) {
                const float x = ((const float*)hr)[u] + hkr[u];     // c*(hq+hk+bq)
                const float e = __builtin_amdgcn_exp2f(x);          // e^{2x}
                const float r = __builtin_amdgcn_rcpf(1.0f + e);
                acc[si] = fmaf(w2c[u], r, acc[si]);                 // += -2W*r
            }
        }
    }

    float Ev[4];
    float part = 0.0f;
#pragma unroll
    for (int si = 0; si < 4; ++si) {
        const float z   = acc[si] + sumW + b_alpha;                       // pre-sigmoid
        const float sgm = __builtin_amdgcn_rcpf(1.0f + __builtin_amdgcn_exp2f(-z * L2E));
        const float e   = __builtin_amdgcn_exp2f(sgm * L2E);              // exp(sigmoid)
        Ev[si] = e;
        part += e;
    }

    float* __restrict__ Erow = E + (size_t)g * TT + s0;
    *(float4*)Erow = make_float4(Ev[0], Ev[1], Ev[2], Ev[3]);

    // block-level reduce of denom partials (4 waves share the same t range)
    __shared__ float red[4][64];
    red[wv][lane] = part;
    __syncthreads();
    if (wv == 0) {
        const float tot = red[0][lane] + red[1][lane] + red[2][lane] + red[3][lane];
        atomicAdd(&denom[g], tot);
    }
}

// ---------------- kernel 2b: wsum[b,s] = (1/T) * sum_t E[b,t,s]/denom[b,t] ----------------
__global__ __launch_bounds__(256) void colsum_kernel(const float* __restrict__ E,
                                                     const float* __restrict__ denom,
                                                     float* __restrict__ wsum)
{
    const int b  = blockIdx.y;
    const int t0 = blockIdx.x * 8;
    const int s  = threadIdx.x;
    float a0 = 0.0f, a1 = 0.0f;
#pragma unroll
    for (int ti = 0; ti < 8; ++ti) {
        const int t = t0 + ti;
        const float rd = 1.0f / denom[b * TT + t];
        const float* __restrict__ Er = E + (size_t)(b * TT + t) * TT;
        a0 = fmaf(Er[s],       rd, a0);
        a1 = fmaf(Er[s + 256], rd, a1);
    }
    atomicAdd(&wsum[b * TT + s],       a0 * (1.0f / TT));
    atomicAdd(&wsum[b * TT + s + 256], a1 * (1.0f / TT));
}

// ---------------- kernel 3: out[b,:] = sum_s wsum[b,s] * h[b,s,:] ----------------
__global__ __launch_bounds__(512) void ctx_kernel(const float* __restrict__ h,
                                                  const float* __restrict__ wsum,
                                                  float* __restrict__ out)
{
    const int b  = blockIdx.y;
    const int s0 = blockIdx.x * 32;
    const int hd = threadIdx.x;
    float a = 0.0f;
#pragma unroll
    for (int si = 0; si < 32; ++si) {
        const int s = s0 + si;
        a = fmaf(wsum[b * TT + s], h[(size_t)(b * TT + s) * HH + hd], a);
    }
    atomicAdd(&out[b * HH + hd], a);
}

extern "C" void kernel_launch(void* const* d_in, const int* in_sizes, int n_in,
                              void* d_out, int out_size, void* d_ws, size_t ws_size,
                              hipStream_t stream)
{
    const float* h       = (const float*)d_in[0];
    const float* Wq      = (const float*)d_in[1];
    const float* Wk      = (const float*)d_in[2];
    const float* bq      = (const float*)d_in[3];
    const float* W       = (const float*)d_in[4];
    const float* b_alpha = (const float*)d_in[5];
    float* out = (float*)d_out;

    float* ws    = (float*)d_ws;
    float* CQ    = ws;                                   // 256*2048 = 524,288 f32 (quad-interleaved)
    float* Ck    = CQ + (size_t)524288;                  // 2048*256 = 524,288 f32
    float* E     = Ck + (size_t)524288;                  // 2048*512 = 1,048,576 f32
    float* denom = E + (size_t)1048576;                  // 2048
    float* wsum  = denom + BB * TT;                      // 2048
    float* w2    = wsum + BB * TT;                       // 256
    float* scal  = w2 + UU;                              // 2
    float* cbq   = scal + 2;                             // 256

    // bf16 staging aliases E (E is only written by score_kernel, after qk_mfma)
    unsigned short* hbf   = (unsigned short*)E;          // 1,048,576 bf16 = 2 MB
    unsigned short* WcatT = hbf + (size_t)1048576;       // 262,144 bf16 = 512 KB

    prep_kernel  <<<64, 256, 0, stream>>>(h, Wq, Wk, bq, W, b_alpha,
                                          hbf, WcatT, cbq, w2, scal, denom, wsum, out);
    qk_mfma      <<<512, 256, 0, stream>>>(hbf, WcatT, cbq, CQ, Ck);
    score_kernel <<<dim3(32, 8, BB), 256, 0, stream>>>(CQ, Ck, w2, scal, E, denom);
    colsum_kernel<<<dim3(64, BB), 256, 0, stream>>>(E, denom, wsum);
    ctx_kernel   <<<dim3(16, BB), 512, 0, stream>>>(h, wsum, out);
}

// Round 4
// 85.198 us; speedup vs baseline: 1.2062x; 1.2062x over previous
//
#include <hip/hip_runtime.h>

#define BB 4
#define TT 512
#define HH 512
#define UU 256

// 2*log2(e): e^{2x} = 2^{c*x}
#define C2L2E 2.8853900817779268f
#define L2E   1.4426950408889634f

typedef __attribute__((ext_vector_type(8))) short bf16x8;
typedef __attribute__((ext_vector_type(4))) float f32x4;

static __device__ inline unsigned short f2bf(float x) {
    union { float f; unsigned u; } v; v.f = x;
    unsigned r = v.u + 0x7fff + ((v.u >> 16) & 1);   // RNE
    return (unsigned short)(r >> 16);
}

// ---------------- prep (513 blocks):
// blocks 0..255   : h -> bf16 (float4 -> ushort4, coalesced)
// blocks 256..511 : WcatT[n][k] = bf16(c*W{q,k}[k][n]) via LDS 32x32 tile transpose
// block 512       : w2/cbq/scal + zero denom/wsum/out
__global__ __launch_bounds__(256) void prep_kernel(const float* __restrict__ h,
                                                   const float* __restrict__ Wq,
                                                   const float* __restrict__ Wk,
                                                   const float* __restrict__ bq,
                                                   const float* __restrict__ W,
                                                   const float* __restrict__ b_alpha,
                                                   unsigned short* __restrict__ hbf,
                                                   unsigned short* __restrict__ WcatT,
                                                   float* __restrict__ cbq,
                                                   float* __restrict__ w2,
                                                   float* __restrict__ scal,
                                                   float* __restrict__ denom,
                                                   float* __restrict__ wsum,
                                                   float* __restrict__ out)
{
    const int blk = blockIdx.x;
    const int tid = threadIdx.x;

    if (blk < 256) {
        const int gid = blk * 256 + tid;                  // 65536 threads
#pragma unroll
        for (int it = 0; it < 4; ++it) {
            const int i = gid + it * 65536;               // 262144 float4 total
            const float4 v = ((const float4*)h)[i];
            ushort4 o;
            o.x = f2bf(v.x); o.y = f2bf(v.y); o.z = f2bf(v.z); o.w = f2bf(v.w);
            ((ushort4*)hbf)[i] = o;
        }
    } else if (blk < 512) {
        __shared__ unsigned short lds[32][33];
        const int tile = blk - 256;                       // 0..255
        const int tn = tile & 15;                         // n-tile
        const int tk = tile >> 4;                         // k-tile
        const int lx = tid & 31;
        const int ly = tid >> 5;                          // 0..7
        const int n = tn * 32 + lx;
#pragma unroll
        for (int kk = ly; kk < 32; kk += 8) {
            const int k = tk * 32 + kk;
            const float v = (n < 256) ? Wq[k * UU + n] : Wk[k * UU + (n - 256)];
            lds[lx][kk] = f2bf(C2L2E * v);
        }
        __syncthreads();
#pragma unroll
        for (int nn = ly; nn < 32; nn += 8) {
            WcatT[(size_t)(tn * 32 + nn) * 512 + tk * 32 + lx] = lds[nn][lx];
        }
    } else {
        __shared__ float red[256];
        const float w = W[tid];
        w2[tid] = -2.0f * w;
        red[tid] = w;
        cbq[tid] = C2L2E * bq[tid];
        __syncthreads();
        for (int off = 128; off > 0; off >>= 1) {
            if (tid < off) red[tid] += red[tid + off];
            __syncthreads();
        }
        if (tid == 0) { scal[0] = red[0]; scal[1] = b_alpha[0]; }
#pragma unroll
        for (int it = 0; it < 8; ++it) {
            const int i = tid + it * 256;                 // 2048
            denom[i] = 0.0f; wsum[i] = 0.0f; out[i] = 0.0f;
        }
    }
}

// ---------------- kernel 1: bf16 MFMA GEMM, M=2048 N=512 K=512 ----------------
// n<256 -> c*hq, stored TRANSPOSED+quad-interleaved: CQ[(u>>2)*8192 + m*4 + (u&3)]
// n>=256 -> c*hk + c*bq, stored row-major: Ck[m*256 + (n-256)]
__global__ __launch_bounds__(256) void qk_mfma(const unsigned short* __restrict__ hbf,
                                               const unsigned short* __restrict__ WcatT,
                                               const float* __restrict__ cbq,
                                               float* __restrict__ CQ,
                                               float* __restrict__ Ck)
{
    const int wave = (blockIdx.x * 256 + threadIdx.x) >> 6;   // 0..2047
    const int lane = threadIdx.x & 63;
    const int mt = wave >> 4;          // 0..127
    const int nt = wave & 15;          // 0..15
    const int m0 = mt * 16, n0 = nt * 32;
    const int lrow = lane & 15;
    const int kgrp = lane >> 4;        // 0..3

    f32x4 acc0 = {0.f, 0.f, 0.f, 0.f};
    f32x4 acc1 = {0.f, 0.f, 0.f, 0.f};
    const unsigned short* Arow = hbf   + (size_t)(m0 + lrow) * 512 + kgrp * 8;
    const unsigned short* B0   = WcatT + (size_t)(n0 + lrow) * 512 + kgrp * 8;
    const unsigned short* B1   = B0 + (size_t)16 * 512;

#pragma unroll
    for (int k0 = 0; k0 < 512; k0 += 32) {
        const bf16x8 a  = *(const bf16x8*)(Arow + k0);
        const bf16x8 b0 = *(const bf16x8*)(B0 + k0);
        const bf16x8 b1 = *(const bf16x8*)(B1 + k0);
        acc0 = __builtin_amdgcn_mfma_f32_16x16x32_bf16(a, b0, acc0, 0, 0, 0);
        acc1 = __builtin_amdgcn_mfma_f32_16x16x32_bf16(a, b1, acc1, 0, 0, 0);
    }

    const int n_0 = n0 + lrow;
    const int n_1 = n_0 + 16;
    if (nt < 8) {
#pragma unroll
        for (int r = 0; r < 4; r++) {
            const int m = m0 + kgrp * 4 + r;
            CQ[(size_t)(n_0 >> 2) * 8192 + m * 4 + (n_0 & 3)] = acc0[r];
            CQ[(size_t)(n_1 >> 2) * 8192 + m * 4 + (n_1 & 3)] = acc1[r];
        }
    } else {
        const float bias0 = cbq[n_0 - 256];
        const float bias1 = cbq[n_1 - 256];
#pragma unroll
        for (int r = 0; r < 4; r++) {
            const int m = m0 + kgrp * 4 + r;
            Ck[(size_t)m * 256 + (n_0 - 256)] = acc0[r] + bias0;
            Ck[(size_t)m * 256 + (n_1 - 256)] = acc1[r] + bias1;
        }
    }
}

// ---------------- kernel 2a: scores + sigmoid + exp, per-(b,t) denom ----------------
// grid (sg=64, tg=8, b=4) = 2048 blocks, 4 waves each -> 8192 waves (8/SIMD).
// lane = t (coalesced CQ); wave owns 2 s (hk rows via wave-uniform s_loads).
__global__ __launch_bounds__(256) void score_kernel(const float* __restrict__ CQ,
                                                    const float* __restrict__ Ck,
                                                    const float* __restrict__ w2,
                                                    const float* __restrict__ scal,
                                                    float* __restrict__ E,
                                                    float* __restrict__ denom)
{
    const int b  = blockIdx.z;
    const int tg = blockIdx.y;
    const int sg = blockIdx.x;
    const int lane = threadIdx.x & 63;
    const int wv = __builtin_amdgcn_readfirstlane((int)(threadIdx.x >> 6));
    const int g  = b * TT + tg * 64 + lane;    // global row (b,t)
    const int s0 = sg * 8 + wv * 2;

    const float sumW    = scal[0];
    const float b_alpha = scal[1];

    float acc[2] = {0.f, 0.f};

    for (int uc = 0; uc < UU; uc += 32) {
        float4 hr[8];
#pragma unroll
        for (int q = 0; q < 8; q++)
            hr[q] = *(const float4*)(CQ + (size_t)(uc / 4 + q) * 8192 + g * 4);
        const float* __restrict__ w2c = w2 + uc;
#pragma unroll
        for (int si = 0; si < 2; ++si) {
            const float* __restrict__ hkr = Ck + (size_t)(b * TT + s0 + si) * UU + uc;
#pragma unroll
            for (int u = 0; u < 32; ++u) {
                const float x = ((const float*)hr)[u] + hkr[u];     // c*(hq+hk+bq)
                const float e = __builtin_amdgcn_exp2f(x);          // e^{2x}
                const float r = __builtin_amdgcn_rcpf(1.0f + e);
                acc[si] = fmaf(w2c[u], r, acc[si]);                 // += -2W*r
            }
        }
    }

    float Ev[2];
    float part = 0.0f;
#pragma unroll
    for (int si = 0; si < 2; ++si) {
        const float z   = acc[si] + sumW + b_alpha;                       // pre-sigmoid
        const float sgm = __builtin_amdgcn_rcpf(1.0f + __builtin_amdgcn_exp2f(-z * L2E));
        const float e   = __builtin_amdgcn_exp2f(sgm * L2E);              // exp(sigmoid)
        Ev[si] = e;
        part += e;
    }

    float* __restrict__ Erow = E + (size_t)g * TT + s0;
    *(float2*)Erow = make_float2(Ev[0], Ev[1]);

    __shared__ float red[4][64];
    red[wv][lane] = part;
    __syncthreads();
    if (wv == 0) {
        const float tot = red[0][lane] + red[1][lane] + red[2][lane] + red[3][lane];
        atomicAdd(&denom[g], tot);
    }
}

// ---------------- kernel 2b: wsum[b,s] = (1/T) * sum_t E[b,t,s]/denom[b,t] ----------------
__global__ __launch_bounds__(256) void colsum_kernel(const float* __restrict__ E,
                                                     const float* __restrict__ denom,
                                                     float* __restrict__ wsum)
{
    const int b  = blockIdx.y;
    const int t0 = blockIdx.x * 4;
    const int s  = threadIdx.x;
    float a0 = 0.0f, a1 = 0.0f;
#pragma unroll
    for (int ti = 0; ti < 4; ++ti) {
        const int t = t0 + ti;
        const float rd = 1.0f / denom[b * TT + t];
        const float* __restrict__ Er = E + (size_t)(b * TT + t) * TT;
        a0 = fmaf(Er[s],       rd, a0);
        a1 = fmaf(Er[s + 256], rd, a1);
    }
    atomicAdd(&wsum[b * TT + s],       a0 * (1.0f / TT));
    atomicAdd(&wsum[b * TT + s + 256], a1 * (1.0f / TT));
}

// ---------------- kernel 3: out[b,:] = sum_s wsum[b,s] * h[b,s,:] ----------------
__global__ __launch_bounds__(512) void ctx_kernel(const float* __restrict__ h,
                                                  const float* __restrict__ wsum,
                                                  float* __restrict__ out)
{
    const int b  = blockIdx.y;
    const int s0 = blockIdx.x * 8;
    const int hd = threadIdx.x;
    float a = 0.0f;
#pragma unroll
    for (int si = 0; si < 8; ++si) {
        const int s = s0 + si;
        a = fmaf(wsum[b * TT + s], h[(size_t)(b * TT + s) * HH + hd], a);
    }
    atomicAdd(&out[b * HH + hd], a);
}

extern "C" void kernel_launch(void* const* d_in, const int* in_sizes, int n_in,
                              void* d_out, int out_size, void* d_ws, size_t ws_size,
                              hipStream_t stream)
{
    const float* h       = (const float*)d_in[0];
    const float* Wq      = (const float*)d_in[1];
    const float* Wk      = (const float*)d_in[2];
    const float* bq      = (const float*)d_in[3];
    const float* W       = (const float*)d_in[4];
    const float* b_alpha = (const float*)d_in[5];
    float* out = (float*)d_out;

    float* ws    = (float*)d_ws;
    float* CQ    = ws;                                   // 524,288 f32 (transposed quad-interleaved)
    float* Ck    = CQ + (size_t)524288;                  // 524,288 f32
    float* E     = Ck + (size_t)524288;                  // 1,048,576 f32
    float* denom = E + (size_t)1048576;                  // 2048
    float* wsum  = denom + BB * TT;                      // 2048
    float* w2    = wsum + BB * TT;                       // 256
    float* scal  = w2 + UU;                              // 2
    float* cbq   = scal + 2;                             // 256

    // bf16 staging aliases E (E is only written by score_kernel, after qk_mfma)
    unsigned short* hbf   = (unsigned short*)E;          // 1,048,576 bf16 = 2 MB
    unsigned short* WcatT = hbf + (size_t)1048576;       // 262,144 bf16 = 512 KB

    prep_kernel  <<<513, 256, 0, stream>>>(h, Wq, Wk, bq, W, b_alpha,
                                           hbf, WcatT, cbq, w2, scal, denom, wsum, out);
    qk_mfma      <<<512, 256, 0, stream>>>(hbf, WcatT, cbq, CQ, Ck);
    score_kernel <<<dim3(64, 8, BB), 256, 0, stream>>>(CQ, Ck, w2, scal, E, denom);
    colsum_kernel<<<dim3(128, BB), 256, 0, stream>>>(E, denom, wsum);
    ctx_kernel   <<<dim3(64, BB), 512, 0, stream>>>(h, wsum, out);
}

// Round 5
// 81.096 us; speedup vs baseline: 1.2672x; 1.0506x over previous
//
#include <hip/hip_runtime.h>

#define BB 4
#define TT 512
#define HH 512
#define UU 256

// 2*log2(e): e^{2x} = 2^{c*x}
#define C2L2E 2.8853900817779268f
#define L2E   1.4426950408889634f

typedef __attribute__((ext_vector_type(8))) short bf16x8;
typedef __attribute__((ext_vector_type(4))) float f32x4;

static __device__ inline unsigned short f2bf(float x) {
    union { float f; unsigned u; } v; v.f = x;
    unsigned r = v.u + 0x7fff + ((v.u >> 16) & 1);   // RNE
    return (unsigned short)(r >> 16);
}

// ---------------- prep (513 blocks):
// blocks 0..255   : h -> bf16 (float4 -> ushort4, coalesced)
// blocks 256..511 : WcatT[n][k] = bf16(c*W{q,k}[k][n]) via LDS 32x32 tile transpose
// block 512       : w2/w2p/cbq/scal + zero denom/wsum/out
__global__ __launch_bounds__(256) void prep_kernel(const float* __restrict__ h,
                                                   const float* __restrict__ Wq,
                                                   const float* __restrict__ Wk,
                                                   const float* __restrict__ bq,
                                                   const float* __restrict__ W,
                                                   const float* __restrict__ b_alpha,
                                                   unsigned short* __restrict__ hbf,
                                                   unsigned short* __restrict__ WcatT,
                                                   float* __restrict__ cbq,
                                                   float* __restrict__ w2,
                                                   float* __restrict__ w2p,
                                                   float* __restrict__ scal,
                                                   float* __restrict__ denom,
                                                   float* __restrict__ wsum,
                                                   float* __restrict__ out)
{
    const int blk = blockIdx.x;
    const int tid = threadIdx.x;

    if (blk < 256) {
        const int gid = blk * 256 + tid;                  // 65536 threads
#pragma unroll
        for (int it = 0; it < 4; ++it) {
            const int i = gid + it * 65536;               // 262144 float4 total
            const float4 v = ((const float4*)h)[i];
            ushort4 o;
            o.x = f2bf(v.x); o.y = f2bf(v.y); o.z = f2bf(v.z); o.w = f2bf(v.w);
            ((ushort4*)hbf)[i] = o;
        }
    } else if (blk < 512) {
        __shared__ unsigned short lds[32][33];
        const int tile = blk - 256;                       // 0..255
        const int tn = tile & 15;                         // n-tile
        const int tk = tile >> 4;                         // k-tile
        const int lx = tid & 31;
        const int ly = tid >> 5;                          // 0..7
        const int n = tn * 32 + lx;
#pragma unroll
        for (int kk = ly; kk < 32; kk += 8) {
            const int k = tk * 32 + kk;
            const float v = (n < 256) ? Wq[k * UU + n] : Wk[k * UU + (n - 256)];
            lds[lx][kk] = f2bf(C2L2E * v);
        }
        __syncthreads();
#pragma unroll
        for (int nn = ly; nn < 32; nn += 8) {
            WcatT[(size_t)(tn * 32 + nn) * 512 + tk * 32 + lx] = lds[nn][lx];
        }
    } else {
        __shared__ float red[256];
        const float w = W[tid];
        w2[tid] = -2.0f * w;
        red[tid] = w;
        cbq[tid] = C2L2E * bq[tid];
        if (tid < 128) w2p[tid] = -2.0f * (W[2 * tid] + W[2 * tid + 1]);
        __syncthreads();
        for (int off = 128; off > 0; off >>= 1) {
            if (tid < off) red[tid] += red[tid + off];
            __syncthreads();
        }
        if (tid == 0) { scal[0] = red[0]; scal[1] = b_alpha[0]; }
#pragma unroll
        for (int it = 0; it < 8; ++it) {
            const int i = tid + it * 256;                 // 2048
            denom[i] = 0.0f; wsum[i] = 0.0f; out[i] = 0.0f;
        }
    }
}

// ---------------- kernel 1: bf16 MFMA GEMM, M=2048 N=512 K=512 ----------------
// n<256 -> c*hq, stored TRANSPOSED+quad-interleaved: CQ[(u>>2)*8192 + m*4 + (u&3)]
// n>=256 -> c*hk + c*bq, stored row-major: Ck[m*256 + (n-256)]
__global__ __launch_bounds__(256) void qk_mfma(const unsigned short* __restrict__ hbf,
                                               const unsigned short* __restrict__ WcatT,
                                               const float* __restrict__ cbq,
                                               float* __restrict__ CQ,
                                               float* __restrict__ Ck)
{
    const int wave = (blockIdx.x * 256 + threadIdx.x) >> 6;   // 0..2047
    const int lane = threadIdx.x & 63;
    const int mt = wave >> 4;          // 0..127
    const int nt = wave & 15;          // 0..15
    const int m0 = mt * 16, n0 = nt * 32;
    const int lrow = lane & 15;
    const int kgrp = lane >> 4;        // 0..3

    f32x4 acc0 = {0.f, 0.f, 0.f, 0.f};
    f32x4 acc1 = {0.f, 0.f, 0.f, 0.f};
    const unsigned short* Arow = hbf   + (size_t)(m0 + lrow) * 512 + kgrp * 8;
    const unsigned short* B0   = WcatT + (size_t)(n0 + lrow) * 512 + kgrp * 8;
    const unsigned short* B1   = B0 + (size_t)16 * 512;

#pragma unroll
    for (int k0 = 0; k0 < 512; k0 += 32) {
        const bf16x8 a  = *(const bf16x8*)(Arow + k0);
        const bf16x8 b0 = *(const bf16x8*)(B0 + k0);
        const bf16x8 b1 = *(const bf16x8*)(B1 + k0);
        acc0 = __builtin_amdgcn_mfma_f32_16x16x32_bf16(a, b0, acc0, 0, 0, 0);
        acc1 = __builtin_amdgcn_mfma_f32_16x16x32_bf16(a, b1, acc1, 0, 0, 0);
    }

    const int n_0 = n0 + lrow;
    const int n_1 = n_0 + 16;
    if (nt < 8) {
#pragma unroll
        for (int r = 0; r < 4; r++) {
            const int m = m0 + kgrp * 4 + r;
            CQ[(size_t)(n_0 >> 2) * 8192 + m * 4 + (n_0 & 3)] = acc0[r];
            CQ[(size_t)(n_1 >> 2) * 8192 + m * 4 + (n_1 & 3)] = acc1[r];
        }
    } else {
        const float bias0 = cbq[n_0 - 256];
        const float bias1 = cbq[n_1 - 256];
#pragma unroll
        for (int r = 0; r < 4; r++) {
            const int m = m0 + kgrp * 4 + r;
            Ck[(size_t)m * 256 + (n_0 - 256)] = acc0[r] + bias0;
            Ck[(size_t)m * 256 + (n_1 - 256)] = acc1[r] + bias1;
        }
    }
}

// ---------------- kernel 2a: scores + sigmoid + exp, per-(b,t) denom ----------------
// grid (sg=64, tg=8, b=4) = 2048 blocks, 4 waves each.
// lane = t (coalesced CQ); wave owns 2 s (hk rows via wave-uniform s_loads).
// Pairwise-combined tanh: w_a/(1+e_a)+w_b/(1+e_b) = (w_ab + w_a e_b + w_b e_a)/((1+e_a)(1+e_b))
__global__ __launch_bounds__(256) void score_kernel(const float* __restrict__ CQ,
                                                    const float* __restrict__ Ck,
                                                    const float* __restrict__ w2,
                                                    const float* __restrict__ w2p,
                                                    const float* __restrict__ scal,
                                                    float* __restrict__ E,
                                                    float* __restrict__ denom)
{
    const int b  = blockIdx.z;
    const int tg = blockIdx.y;
    const int sg = blockIdx.x;
    const int lane = threadIdx.x & 63;
    const int wv = __builtin_amdgcn_readfirstlane((int)(threadIdx.x >> 6));
    const int g  = b * TT + tg * 64 + lane;    // global row (b,t)
    const int s0 = sg * 8 + wv * 2;

    const float sumW    = scal[0];
    const float b_alpha = scal[1];

    float acc[2][2] = {{0.f, 0.f}, {0.f, 0.f}};

    for (int uc = 0; uc < UU; uc += 32) {
        float4 hr[8];
#pragma unroll
        for (int q = 0; q < 8; q++)
            hr[q] = *(const float4*)(CQ + (size_t)(uc / 4 + q) * 8192 + g * 4);
        const float* __restrict__ hf   = (const float*)hr;
        const float* __restrict__ w2c  = w2 + uc;
        const float* __restrict__ w2pc = w2p + uc / 2;
#pragma unroll
        for (int si = 0; si < 2; ++si) {
            const float* __restrict__ hkr = Ck + (size_t)(b * TT + s0 + si) * UU + uc;
#pragma unroll
            for (int p = 0; p < 16; ++p) {
                const float xa = hf[2 * p]     + hkr[2 * p];
                const float xb = hf[2 * p + 1] + hkr[2 * p + 1];
                const float ea = __builtin_amdgcn_exp2f(xa);
                const float eb = __builtin_amdgcn_exp2f(xb);
                const float t  = ea + 1.0f;
                const float dn = fmaf(t, eb, t);                   // (1+ea)(1+eb)
                float num = fmaf(w2c[2 * p], eb, w2pc[p]);
                num = fmaf(w2c[2 * p + 1], ea, num);
                const float r = __builtin_amdgcn_rcpf(dn);
                acc[si][p & 1] = fmaf(num, r, acc[si][p & 1]);
            }
        }
    }

    float Ev[2];
    float part = 0.0f;
#pragma unroll
    for (int si = 0; si < 2; ++si) {
        const float z   = acc[si][0] + acc[si][1] + sumW + b_alpha;       // pre-sigmoid
        const float sgm = __builtin_amdgcn_rcpf(1.0f + __builtin_amdgcn_exp2f(-z * L2E));
        const float e   = __builtin_amdgcn_exp2f(sgm * L2E);              // exp(sigmoid)
        Ev[si] = e;
        part += e;
    }

    float* __restrict__ Erow = E + (size_t)g * TT + s0;
    *(float2*)Erow = make_float2(Ev[0], Ev[1]);

    __shared__ float red[4][64];
    red[wv][lane] = part;
    __syncthreads();
    if (wv == 0) {
        const float tot = red[0][lane] + red[1][lane] + red[2][lane] + red[3][lane];
        atomicAdd(&denom[g], tot);
    }
}

// ---------------- kernel 2b: wsum[b,s] = (1/T) * sum_t E[b,t,s]/denom[b,t] ----------------
__global__ __launch_bounds__(256) void colsum_kernel(const float* __restrict__ E,
                                                     const float* __restrict__ denom,
                                                     float* __restrict__ wsum)
{
    const int b  = blockIdx.y;
    const int t0 = blockIdx.x * 4;
    const int s  = threadIdx.x;
    float a0 = 0.0f, a1 = 0.0f;
#pragma unroll
    for (int ti = 0; ti < 4; ++ti) {
        const int t = t0 + ti;
        const float rd = 1.0f / denom[b * TT + t];
        const float* __restrict__ Er = E + (size_t)(b * TT + t) * TT;
        a0 = fmaf(Er[s],       rd, a0);
        a1 = fmaf(Er[s + 256], rd, a1);
    }
    atomicAdd(&wsum[b * TT + s],       a0 * (1.0f / TT));
    atomicAdd(&wsum[b * TT + s + 256], a1 * (1.0f / TT));
}

// ---------------- kernel 3: out[b,:] = sum_s wsum[b,s] * h[b,s,:] ----------------
__global__ __launch_bounds__(512) void ctx_kernel(const float* __restrict__ h,
                                                  const float* __restrict__ wsum,
                                                  float* __restrict__ out)
{
    const int b  = blockIdx.y;
    const int s0 = blockIdx.x * 8;
    const int hd = threadIdx.x;
    float a = 0.0f;
#pragma unroll
    for (int si = 0; si < 8; ++si) {
        const int s = s0 + si;
        a = fmaf(wsum[b * TT + s], h[(size_t)(b * TT + s) * HH + hd], a);
    }
    atomicAdd(&out[b * HH + hd], a);
}

extern "C" void kernel_launch(void* const* d_in, const int* in_sizes, int n_in,
                              void* d_out, int out_size, void* d_ws, size_t ws_size,
                              hipStream_t stream)
{
    const float* h       = (const float*)d_in[0];
    const float* Wq      = (const float*)d_in[1];
    const float* Wk      = (const float*)d_in[2];
    const float* bq      = (const float*)d_in[3];
    const float* W       = (const float*)d_in[4];
    const float* b_alpha = (const float*)d_in[5];
    float* out = (float*)d_out;

    float* ws    = (float*)d_ws;
    float* CQ    = ws;                                   // 524,288 f32 (transposed quad-interleaved)
    float* Ck    = CQ + (size_t)524288;                  // 524,288 f32
    float* E     = Ck + (size_t)524288;                  // 1,048,576 f32
    float* denom = E + (size_t)1048576;                  // 2048
    float* wsum  = denom + BB * TT;                      // 2048
    float* w2    = wsum + BB * TT;                       // 256
    float* w2p   = w2 + UU;                              // 128
    float* scal  = w2p + 128;                            // 2
    float* cbq   = scal + 2;                             // 256

    // bf16 staging aliases E (E is only written by score_kernel, after qk_mfma)
    unsigned short* hbf   = (unsigned short*)E;          // 1,048,576 bf16 = 2 MB
    unsigned short* WcatT = hbf + (size_t)1048576;       // 262,144 bf16 = 512 KB

    prep_kernel  <<<513, 256, 0, stream>>>(h, Wq, Wk, bq, W, b_alpha,
                                           hbf, WcatT, cbq, w2, w2p, scal, denom, wsum, out);
    qk_mfma      <<<512, 256, 0, stream>>>(hbf, WcatT, cbq, CQ, Ck);
    score_kernel <<<dim3(64, 8, BB), 256, 0, stream>>>(CQ, Ck, w2, w2p, scal, E, denom);
    colsum_kernel<<<dim3(128, BB), 256, 0, stream>>>(E, denom, wsum);
    ctx_kernel   <<<dim3(64, BB), 512, 0, stream>>>(h, wsum, out);
}

// Round 6
// 75.578 us; speedup vs baseline: 1.3597x; 1.0730x over previous
//
#include <hip/hip_runtime.h>

#define BB 4
#define TT 512
#define HH 512
#define UU 256

// 2*log2(e): e^{2x} = 2^{c*x}
#define C2L2E 2.8853900817779268f
#define L2E   1.4426950408889634f

typedef __attribute__((ext_vector_type(8))) short bf16x8;
typedef __attribute__((ext_vector_type(4))) float f32x4;

static __device__ inline unsigned short f2bf(float x) {
    union { float f; unsigned u; } v; v.f = x;
    unsigned r = v.u + 0x7fff + ((v.u >> 16) & 1);   // RNE
    return (unsigned short)(r >> 16);
}

// ---------------- prep (513 blocks):
// blocks 0..255   : h -> bf16 (float4 -> ushort4, coalesced)
// blocks 256..511 : WcatT[n][k] = bf16(c*W{q,k}[k][n]) via LDS 32x32 tile transpose
// block 512       : w2/w2p/cbq/scal + zero denom/wsum/out
__global__ __launch_bounds__(256) void prep_kernel(const float* __restrict__ h,
                                                   const float* __restrict__ Wq,
                                                   const float* __restrict__ Wk,
                                                   const float* __restrict__ bq,
                                                   const float* __restrict__ W,
                                                   const float* __restrict__ b_alpha,
                                                   unsigned short* __restrict__ hbf,
                                                   unsigned short* __restrict__ WcatT,
                                                   float* __restrict__ cbq,
                                                   float* __restrict__ w2,
                                                   float* __restrict__ w2p,
                                                   float* __restrict__ scal,
                                                   float* __restrict__ denom,
                                                   float* __restrict__ wsum,
                                                   float* __restrict__ out)
{
    const int blk = blockIdx.x;
    const int tid = threadIdx.x;

    if (blk < 256) {
        const int gid = blk * 256 + tid;                  // 65536 threads
#pragma unroll
        for (int it = 0; it < 4; ++it) {
            const int i = gid + it * 65536;               // 262144 float4 total
            const float4 v = ((const float4*)h)[i];
            ushort4 o;
            o.x = f2bf(v.x); o.y = f2bf(v.y); o.z = f2bf(v.z); o.w = f2bf(v.w);
            ((ushort4*)hbf)[i] = o;
        }
    } else if (blk < 512) {
        __shared__ unsigned short lds[32][33];
        const int tile = blk - 256;                       // 0..255
        const int tn = tile & 15;                         // n-tile
        const int tk = tile >> 4;                         // k-tile
        const int lx = tid & 31;
        const int ly = tid >> 5;                          // 0..7
        const int n = tn * 32 + lx;
#pragma unroll
        for (int kk = ly; kk < 32; kk += 8) {
            const int k = tk * 32 + kk;
            const float v = (n < 256) ? Wq[k * UU + n] : Wk[k * UU + (n - 256)];
            lds[lx][kk] = f2bf(C2L2E * v);
        }
        __syncthreads();
#pragma unroll
        for (int nn = ly; nn < 32; nn += 8) {
            WcatT[(size_t)(tn * 32 + nn) * 512 + tk * 32 + lx] = lds[nn][lx];
        }
    } else {
        __shared__ float red[256];
        const float w = W[tid];
        w2[tid] = -2.0f * w;
        red[tid] = w;
        cbq[tid] = C2L2E * bq[tid];
        if (tid < 128) w2p[tid] = -2.0f * (W[2 * tid] + W[2 * tid + 1]);
        __syncthreads();
        for (int off = 128; off > 0; off >>= 1) {
            if (tid < off) red[tid] += red[tid + off];
            __syncthreads();
        }
        if (tid == 0) { scal[0] = red[0]; scal[1] = b_alpha[0]; }
#pragma unroll
        for (int it = 0; it < 8; ++it) {
            const int i = tid + it * 256;                 // 2048
            denom[i] = 0.0f; wsum[i] = 0.0f; out[i] = 0.0f;
        }
    }
}

// ---------------- kernel 1: bf16 MFMA GEMM + exp2 epilogue ----------------
// M=2048, N=512, K=512.
// n<256  -> EQ = exp2(c*hq), stored TRANSPOSED quad-interleaved: EQ[(u>>2)*8192 + m*4 + (u&3)]
// n>=256 -> EK = exp2(c*hk + c*bq), stored row-major: EKm[m*256 + (n-256)]
__global__ __launch_bounds__(256) void qk_mfma(const unsigned short* __restrict__ hbf,
                                               const unsigned short* __restrict__ WcatT,
                                               const float* __restrict__ cbq,
                                               float* __restrict__ EQ,
                                               float* __restrict__ EKm)
{
    const int wave = (blockIdx.x * 256 + threadIdx.x) >> 6;   // 0..2047
    const int lane = threadIdx.x & 63;
    const int mt = wave >> 4;          // 0..127
    const int nt = wave & 15;          // 0..15
    const int m0 = mt * 16, n0 = nt * 32;
    const int lrow = lane & 15;
    const int kgrp = lane >> 4;        // 0..3

    f32x4 acc0 = {0.f, 0.f, 0.f, 0.f};
    f32x4 acc1 = {0.f, 0.f, 0.f, 0.f};
    const unsigned short* Arow = hbf   + (size_t)(m0 + lrow) * 512 + kgrp * 8;
    const unsigned short* B0   = WcatT + (size_t)(n0 + lrow) * 512 + kgrp * 8;
    const unsigned short* B1   = B0 + (size_t)16 * 512;

#pragma unroll
    for (int k0 = 0; k0 < 512; k0 += 32) {
        const bf16x8 a  = *(const bf16x8*)(Arow + k0);
        const bf16x8 b0 = *(const bf16x8*)(B0 + k0);
        const bf16x8 b1 = *(const bf16x8*)(B1 + k0);
        acc0 = __builtin_amdgcn_mfma_f32_16x16x32_bf16(a, b0, acc0, 0, 0, 0);
        acc1 = __builtin_amdgcn_mfma_f32_16x16x32_bf16(a, b1, acc1, 0, 0, 0);
    }

    const int n_0 = n0 + lrow;
    const int n_1 = n_0 + 16;
    if (nt < 8) {
#pragma unroll
        for (int r = 0; r < 4; r++) {
            const int m = m0 + kgrp * 4 + r;
            EQ[(size_t)(n_0 >> 2) * 8192 + m * 4 + (n_0 & 3)] = __builtin_amdgcn_exp2f(acc0[r]);
            EQ[(size_t)(n_1 >> 2) * 8192 + m * 4 + (n_1 & 3)] = __builtin_amdgcn_exp2f(acc1[r]);
        }
    } else {
        const float bias0 = cbq[n_0 - 256];
        const float bias1 = cbq[n_1 - 256];
#pragma unroll
        for (int r = 0; r < 4; r++) {
            const int m = m0 + kgrp * 4 + r;
            EKm[(size_t)m * 256 + (n_0 - 256)] = __builtin_amdgcn_exp2f(acc0[r] + bias0);
            EKm[(size_t)m * 256 + (n_1 - 256)] = __builtin_amdgcn_exp2f(acc1[r] + bias1);
        }
    }
}

// ---------------- kernel 2a: scores + sigmoid + exp, per-(b,t) denom ----------------
// grid (sg=64, tg=8, b=4) = 2048 blocks, 4 waves each. lane = t; wave owns 2 s.
// e_u = EQ[t,u] * EK[s,u]  (no exp2 in the hot loop!)
// Quad-rational: w2a/(1+e1)+w2b/(1+e2) = (w2p + w2a*e2 + w2b*e1)/((1+e1)(1+e2)), pairs combined.
__global__ __launch_bounds__(256) void score_kernel(const float* __restrict__ EQ,
                                                    const float* __restrict__ EKm,
                                                    const float* __restrict__ w2,
                                                    const float* __restrict__ w2p,
                                                    const float* __restrict__ scal,
                                                    float* __restrict__ E,
                                                    float* __restrict__ denom)
{
    const int b  = blockIdx.z;
    const int tg = blockIdx.y;
    const int sg = blockIdx.x;
    const int tid  = threadIdx.x;
    const int lane = tid & 63;
    const int wv = __builtin_amdgcn_readfirstlane((int)(tid >> 6));
    const int g  = b * TT + tg * 64 + lane;    // global row (b,t)

    __shared__ float khk[8][256];   // EK rows for this block's 8 s
    __shared__ float w2l[256];
    __shared__ float w2pl[128];
    __shared__ float red[4][64];

    {   // stage: 8 rows x 256 floats, coalesced
        const int r = tid >> 5;
        const int c = (tid & 31) * 8;
        const float* src = EKm + (size_t)(b * TT + sg * 8 + r) * 256 + c;
        *(float4*)&khk[r][c]     = *(const float4*)(src);
        *(float4*)&khk[r][c + 4] = *(const float4*)(src + 4);
        w2l[tid] = w2[tid];
        if (tid < 128) w2pl[tid] = w2p[tid];
    }
    __syncthreads();

    const float sumW    = scal[0];
    const float b_alpha = scal[1];

    float acc[2][2] = {{0.f, 0.f}, {0.f, 0.f}};

    for (int uc = 0; uc < UU; uc += 32) {
        float4 hr[8];
#pragma unroll
        for (int q = 0; q < 8; q++)
            hr[q] = *(const float4*)(EQ + (size_t)(uc / 4 + q) * 8192 + g * 4);
        const float* __restrict__ hf = (const float*)hr;
#pragma unroll
        for (int si = 0; si < 2; ++si) {
            const float* __restrict__ ekr = &khk[2 * wv + si][0];
#pragma unroll
            for (int qd = 0; qd < 8; ++qd) {
                const int u = uc + 4 * qd;
                const float4 ek = *(const float4*)(ekr + u);
                const float4 wq = *(const float4*)(&w2l[u]);
                const float2 wp = *(const float2*)(&w2pl[u >> 1]);
                const float e1 = hf[4 * qd + 0] * ek.x;
                const float e2 = hf[4 * qd + 1] * ek.y;
                const float e3 = hf[4 * qd + 2] * ek.z;
                const float e4 = hf[4 * qd + 3] * ek.w;
                const float t1 = 1.0f + e1;
                const float d1 = fmaf(t1, e2, t1);                 // (1+e1)(1+e2)
                float n1 = fmaf(wq.x, e2, wp.x);
                n1 = fmaf(wq.y, e1, n1);
                const float t3 = 1.0f + e3;
                const float d2 = fmaf(t3, e4, t3);                 // (1+e3)(1+e4)
                float n2 = fmaf(wq.z, e4, wp.y);
                n2 = fmaf(wq.w, e3, n2);
                const float d = d1 * d2;
                float n = n1 * d2;
                n = fmaf(n2, d1, n);
                const float r = __builtin_amdgcn_rcpf(d);
                acc[si][qd & 1] = fmaf(n, r, acc[si][qd & 1]);
            }
        }
    }

    const int s0 = sg * 8 + wv * 2;
    float Ev[2];
    float part = 0.0f;
#pragma unroll
    for (int si = 0; si < 2; ++si) {
        const float z   = acc[si][0] + acc[si][1] + sumW + b_alpha;       // pre-sigmoid
        const float sgm = __builtin_amdgcn_rcpf(1.0f + __builtin_amdgcn_exp2f(-z * L2E));
        const float e   = __builtin_amdgcn_exp2f(sgm * L2E);              // exp(sigmoid)
        Ev[si] = e;
        part += e;
    }

    float* __restrict__ Erow = E + (size_t)g * TT + s0;
    *(float2*)Erow = make_float2(Ev[0], Ev[1]);

    red[wv][lane] = part;
    __syncthreads();
    if (wv == 0) {
        const float tot = red[0][lane] + red[1][lane] + red[2][lane] + red[3][lane];
        atomicAdd(&denom[g], tot);
    }
}

// ---------------- kernel 2b: wsum[b,s] = (1/T) * sum_t E[b,t,s]/denom[b,t] ----------------
__global__ __launch_bounds__(256) void colsum_kernel(const float* __restrict__ E,
                                                     const float* __restrict__ denom,
                                                     float* __restrict__ wsum)
{
    const int b  = blockIdx.y;
    const int t0 = blockIdx.x * 4;
    const int s  = threadIdx.x;
    float a0 = 0.0f, a1 = 0.0f;
#pragma unroll
    for (int ti = 0; ti < 4; ++ti) {
        const int t = t0 + ti;
        const float rd = 1.0f / denom[b * TT + t];
        const float* __restrict__ Er = E + (size_t)(b * TT + t) * TT;
        a0 = fmaf(Er[s],       rd, a0);
        a1 = fmaf(Er[s + 256], rd, a1);
    }
    atomicAdd(&wsum[b * TT + s],       a0 * (1.0f / TT));
    atomicAdd(&wsum[b * TT + s + 256], a1 * (1.0f / TT));
}

// ---------------- kernel 3: out[b,:] = sum_s wsum[b,s] * h[b,s,:] ----------------
__global__ __launch_bounds__(512) void ctx_kernel(const float* __restrict__ h,
                                                  const float* __restrict__ wsum,
                                                  float* __restrict__ out)
{
    const int b  = blockIdx.y;
    const int s0 = blockIdx.x * 8;
    const int hd = threadIdx.x;
    float a = 0.0f;
#pragma unroll
    for (int si = 0; si < 8; ++si) {
        const int s = s0 + si;
        a = fmaf(wsum[b * TT + s], h[(size_t)(b * TT + s) * HH + hd], a);
    }
    atomicAdd(&out[b * HH + hd], a);
}

extern "C" void kernel_launch(void* const* d_in, const int* in_sizes, int n_in,
                              void* d_out, int out_size, void* d_ws, size_t ws_size,
                              hipStream_t stream)
{
    const float* h       = (const float*)d_in[0];
    const float* Wq      = (const float*)d_in[1];
    const float* Wk      = (const float*)d_in[2];
    const float* bq      = (const float*)d_in[3];
    const float* W       = (const float*)d_in[4];
    const float* b_alpha = (const float*)d_in[5];
    float* out = (float*)d_out;

    float* ws    = (float*)d_ws;
    float* EQ    = ws;                                   // 524,288 f32 (transposed quad-interleaved)
    float* EKm   = EQ + (size_t)524288;                  // 524,288 f32
    float* E     = EKm + (size_t)524288;                 // 1,048,576 f32
    float* denom = E + (size_t)1048576;                  // 2048
    float* wsum  = denom + BB * TT;                      // 2048
    float* w2    = wsum + BB * TT;                       // 256
    float* w2p   = w2 + UU;                              // 128
    float* scal  = w2p + 128;                            // 2
    float* cbq   = scal + 2;                             // 256

    // bf16 staging aliases E (E is only written by score_kernel, after qk_mfma)
    unsigned short* hbf   = (unsigned short*)E;          // 1,048,576 bf16 = 2 MB
    unsigned short* WcatT = hbf + (size_t)1048576;       // 262,144 bf16 = 512 KB

    prep_kernel  <<<513, 256, 0, stream>>>(h, Wq, Wk, bq, W, b_alpha,
                                           hbf, WcatT, cbq, w2, w2p, scal, denom, wsum, out);
    qk_mfma      <<<512, 256, 0, stream>>>(hbf, WcatT, cbq, EQ, EKm);
    score_kernel <<<dim3(64, 8, BB), 256, 0, stream>>>(EQ, EKm, w2, w2p, scal, E, denom);
    colsum_kernel<<<dim3(128, BB), 256, 0, stream>>>(E, denom, wsum);
    ctx_kernel   <<<dim3(64, BB), 512, 0, stream>>>(h, wsum, out);
}

// Round 7
// 74.698 us; speedup vs baseline: 1.3758x; 1.0118x over previous
//
#include <hip/hip_runtime.h>

#define BB 4
#define TT 512
#define HH 512
#define UU 256

// 2*log2(e): e^{2x} = 2^{c*x}
#define C2L2E 2.8853900817779268f
#define L2E   1.4426950408889634f

typedef __attribute__((ext_vector_type(8))) short bf16x8;
typedef __attribute__((ext_vector_type(4))) float f32x4;
typedef __attribute__((ext_vector_type(2))) float f32x2;

static __device__ inline unsigned short f2bf(float x) {
    union { float f; unsigned u; } v; v.f = x;
    unsigned r = v.u + 0x7fff + ((v.u >> 16) & 1);   // RNE
    return (unsigned short)(r >> 16);
}

static __device__ inline f32x2 pk_mul(f32x2 a, f32x2 b) {
    f32x2 d; asm("v_pk_mul_f32 %0, %1, %2" : "=v"(d) : "v"(a), "v"(b)); return d;
}
static __device__ inline f32x2 pk_add(f32x2 a, f32x2 b) {
    f32x2 d; asm("v_pk_add_f32 %0, %1, %2" : "=v"(d) : "v"(a), "v"(b)); return d;
}
static __device__ inline f32x2 pk_fma(f32x2 a, f32x2 b, f32x2 c) {
    f32x2 d; asm("v_pk_fma_f32 %0, %1, %2, %3" : "=v"(d) : "v"(a), "v"(b), "v"(c)); return d;
}

// ---------------- prep (513 blocks):
// blocks 0..255   : h -> bf16 (float4 -> ushort4, coalesced)
// blocks 256..511 : WcatT[n][k] = bf16(c*W{q,k}[k][n]) via LDS 32x32 tile transpose
// block 512       : w2/w2p/cbq/scal + zero denom/wsum/out
// Pairing for w2p: quad u=4q pairs (4q,4q+2) and (4q+1,4q+3):
//   w2p[2q]   = -2*(W[4q]   + W[4q+2])
//   w2p[2q+1] = -2*(W[4q+1] + W[4q+3])
__global__ __launch_bounds__(256) void prep_kernel(const float* __restrict__ h,
                                                   const float* __restrict__ Wq,
                                                   const float* __restrict__ Wk,
                                                   const float* __restrict__ bq,
                                                   const float* __restrict__ W,
                                                   const float* __restrict__ b_alpha,
                                                   unsigned short* __restrict__ hbf,
                                                   unsigned short* __restrict__ WcatT,
                                                   float* __restrict__ cbq,
                                                   float* __restrict__ w2,
                                                   float* __restrict__ w2p,
                                                   float* __restrict__ scal,
                                                   float* __restrict__ denom,
                                                   float* __restrict__ wsum,
                                                   float* __restrict__ out)
{
    const int blk = blockIdx.x;
    const int tid = threadIdx.x;

    if (blk < 256) {
        const int gid = blk * 256 + tid;                  // 65536 threads
#pragma unroll
        for (int it = 0; it < 4; ++it) {
            const int i = gid + it * 65536;               // 262144 float4 total
            const float4 v = ((const float4*)h)[i];
            ushort4 o;
            o.x = f2bf(v.x); o.y = f2bf(v.y); o.z = f2bf(v.z); o.w = f2bf(v.w);
            ((ushort4*)hbf)[i] = o;
        }
    } else if (blk < 512) {
        __shared__ unsigned short lds[32][33];
        const int tile = blk - 256;                       // 0..255
        const int tn = tile & 15;                         // n-tile
        const int tk = tile >> 4;                         // k-tile
        const int lx = tid & 31;
        const int ly = tid >> 5;                          // 0..7
        const int n = tn * 32 + lx;
#pragma unroll
        for (int kk = ly; kk < 32; kk += 8) {
            const int k = tk * 32 + kk;
            const float v = (n < 256) ? Wq[k * UU + n] : Wk[k * UU + (n - 256)];
            lds[lx][kk] = f2bf(C2L2E * v);
        }
        __syncthreads();
#pragma unroll
        for (int nn = ly; nn < 32; nn += 8) {
            WcatT[(size_t)(tn * 32 + nn) * 512 + tk * 32 + lx] = lds[nn][lx];
        }
    } else {
        __shared__ float red[256];
        const float w = W[tid];
        w2[tid] = -2.0f * w;
        red[tid] = w;
        cbq[tid] = C2L2E * bq[tid];
        if (tid < 64) {
            w2p[2 * tid]     = -2.0f * (W[4 * tid]     + W[4 * tid + 2]);
            w2p[2 * tid + 1] = -2.0f * (W[4 * tid + 1] + W[4 * tid + 3]);
        }
        __syncthreads();
        for (int off = 128; off > 0; off >>= 1) {
            if (tid < off) red[tid] += red[tid + off];
            __syncthreads();
        }
        if (tid == 0) { scal[0] = red[0]; scal[1] = b_alpha[0]; }
#pragma unroll
        for (int it = 0; it < 8; ++it) {
            const int i = tid + it * 256;                 // 2048
            denom[i] = 0.0f; wsum[i] = 0.0f; out[i] = 0.0f;
        }
    }
}

// ---------------- kernel 1: bf16 MFMA GEMM + exp2 epilogue ----------------
// M=2048, N=512, K=512.
// n<256  -> EQ = exp2(c*hq), stored TRANSPOSED quad-interleaved: EQ[(u>>2)*8192 + m*4 + (u&3)]
// n>=256 -> EK = exp2(c*hk + c*bq), stored row-major: EKm[m*256 + (n-256)]
__global__ __launch_bounds__(256) void qk_mfma(const unsigned short* __restrict__ hbf,
                                               const unsigned short* __restrict__ WcatT,
                                               const float* __restrict__ cbq,
                                               float* __restrict__ EQ,
                                               float* __restrict__ EKm)
{
    const int wave = (blockIdx.x * 256 + threadIdx.x) >> 6;   // 0..2047
    const int lane = threadIdx.x & 63;
    const int mt = wave >> 4;          // 0..127
    const int nt = wave & 15;          // 0..15
    const int m0 = mt * 16, n0 = nt * 32;
    const int lrow = lane & 15;
    const int kgrp = lane >> 4;        // 0..3

    f32x4 acc0 = {0.f, 0.f, 0.f, 0.f};
    f32x4 acc1 = {0.f, 0.f, 0.f, 0.f};
    const unsigned short* Arow = hbf   + (size_t)(m0 + lrow) * 512 + kgrp * 8;
    const unsigned short* B0   = WcatT + (size_t)(n0 + lrow) * 512 + kgrp * 8;
    const unsigned short* B1   = B0 + (size_t)16 * 512;

#pragma unroll
    for (int k0 = 0; k0 < 512; k0 += 32) {
        const bf16x8 a  = *(const bf16x8*)(Arow + k0);
        const bf16x8 b0 = *(const bf16x8*)(B0 + k0);
        const bf16x8 b1 = *(const bf16x8*)(B1 + k0);
        acc0 = __builtin_amdgcn_mfma_f32_16x16x32_bf16(a, b0, acc0, 0, 0, 0);
        acc1 = __builtin_amdgcn_mfma_f32_16x16x32_bf16(a, b1, acc1, 0, 0, 0);
    }

    const int n_0 = n0 + lrow;
    const int n_1 = n_0 + 16;
    if (nt < 8) {
#pragma unroll
        for (int r = 0; r < 4; r++) {
            const int m = m0 + kgrp * 4 + r;
            EQ[(size_t)(n_0 >> 2) * 8192 + m * 4 + (n_0 & 3)] = __builtin_amdgcn_exp2f(acc0[r]);
            EQ[(size_t)(n_1 >> 2) * 8192 + m * 4 + (n_1 & 3)] = __builtin_amdgcn_exp2f(acc1[r]);
        }
    } else {
        const float bias0 = cbq[n_0 - 256];
        const float bias1 = cbq[n_1 - 256];
#pragma unroll
        for (int r = 0; r < 4; r++) {
            const int m = m0 + kgrp * 4 + r;
            EKm[(size_t)m * 256 + (n_0 - 256)] = __builtin_amdgcn_exp2f(acc0[r] + bias0);
            EKm[(size_t)m * 256 + (n_1 - 256)] = __builtin_amdgcn_exp2f(acc1[r] + bias1);
        }
    }
}

// ---------------- kernel 2a: scores + sigmoid + exp, per-(b,t) denom ----------------
// grid (sg=64, tg=8, b=4) = 2048 blocks, 4 waves each = 8 blocks/CU fully resident.
// lane = t; wave owns 2 s. e_u = EQ[t,u]*EK[s,u].
// Packed quad-rational over pairs (u0,u2),(u1,u3):
//   halves of each f32x2 = the two pairs; combine cross-half with 3 scalar ops + 1 rcp.
__global__ __launch_bounds__(256, 8) void score_kernel(const float* __restrict__ EQ,
                                                       const float* __restrict__ EKm,
                                                       const float* __restrict__ w2,
                                                       const float* __restrict__ w2p,
                                                       const float* __restrict__ scal,
                                                       float* __restrict__ E,
                                                       float* __restrict__ denom)
{
    const int b  = blockIdx.z;
    const int tg = blockIdx.y;
    const int sg = blockIdx.x;
    const int tid  = threadIdx.x;
    const int lane = tid & 63;
    const int wv = __builtin_amdgcn_readfirstlane((int)(tid >> 6));
    const int g  = b * TT + tg * 64 + lane;    // global row (b,t)

    __shared__ float khk[2048];     // 8 rows x 256 (flat, conflict-free staging)
    __shared__ float w2l[256];
    __shared__ float w2pl[128];
    __shared__ float red[4][64];

    {   // stage: each thread writes 2 b128 at consecutive per-lane addresses
        const float* srcb = EKm + (size_t)(b * TT + sg * 8) * 256;
        *(float4*)&khk[tid * 4]        = *(const float4*)(srcb + tid * 4);
        *(float4*)&khk[tid * 4 + 1024] = *(const float4*)(srcb + tid * 4 + 1024);
        w2l[tid] = w2[tid];
        if (tid < 128) w2pl[tid] = w2p[tid];
    }
    __syncthreads();

    const float sumW    = scal[0];
    const float b_alpha = scal[1];
    const f32x2 kOne = {1.0f, 1.0f};

    const float* __restrict__ ek0b = &khk[(2 * wv + 0) * 256];
    const float* __restrict__ ek1b = &khk[(2 * wv + 1) * 256];

    float acc[2][2] = {{0.f, 0.f}, {0.f, 0.f}};

    for (int uc = 0; uc < UU; uc += 16) {
        f32x4 hr[4];
#pragma unroll
        for (int q = 0; q < 4; q++)
            hr[q] = *(const f32x4*)(EQ + (size_t)(uc / 4 + q) * 8192 + g * 4);
#pragma unroll
        for (int qd = 0; qd < 4; ++qd) {
            const int u = uc + 4 * qd;
            const f32x2 hf01 = __builtin_shufflevector(hr[qd], hr[qd], 0, 1);
            const f32x2 hf23 = __builtin_shufflevector(hr[qd], hr[qd], 2, 3);
            const f32x4 wv4  = *(const f32x4*)&w2l[u];
            const f32x2 w01  = __builtin_shufflevector(wv4, wv4, 0, 1);
            const f32x2 w23  = __builtin_shufflevector(wv4, wv4, 2, 3);
            const f32x2 wp   = *(const f32x2*)&w2pl[u >> 1];
#pragma unroll
            for (int si = 0; si < 2; ++si) {
                const float* __restrict__ ekb = si ? ek1b : ek0b;
                const f32x4 ekv  = *(const f32x4*)&ekb[u];
                const f32x2 ek01 = __builtin_shufflevector(ekv, ekv, 0, 1);
                const f32x2 ek23 = __builtin_shufflevector(ekv, ekv, 2, 3);
                const f32x2 ev0 = pk_mul(hf01, ek01);          // (e0, e1)
                const f32x2 ev1 = pk_mul(hf23, ek23);          // (e2, e3)
                const f32x2 t   = pk_add(ev0, kOne);           // (1+e0, 1+e1)
                const f32x2 d   = pk_fma(t, ev1, t);           // ((1+e0)(1+e2), (1+e1)(1+e3))
                f32x2 n = pk_fma(w01, ev1, wp);                // wp + w0*e2 | w1*e3
                n = pk_fma(w23, ev0, n);                       //    + w2*e0 | w3*e1
                const float dq = d.x * d.y;
                const float nq = fmaf(n.y, d.x, n.x * d.y);
                const float r  = __builtin_amdgcn_rcpf(dq);
                acc[si][qd & 1] = fmaf(nq, r, acc[si][qd & 1]);
            }
        }
    }

    const int s0 = sg * 8 + wv * 2;
    float Ev[2];
    float part = 0.0f;
#pragma unroll
    for (int si = 0; si < 2; ++si) {
        const float z   = acc[si][0] + acc[si][1] + sumW + b_alpha;       // pre-sigmoid
        const float sgm = __builtin_amdgcn_rcpf(1.0f + __builtin_amdgcn_exp2f(-z * L2E));
        const float e   = __builtin_amdgcn_exp2f(sgm * L2E);              // exp(sigmoid)
        Ev[si] = e;
        part += e;
    }

    float* __restrict__ Erow = E + (size_t)g * TT + s0;
    *(float2*)Erow = make_float2(Ev[0], Ev[1]);

    red[wv][lane] = part;
    __syncthreads();
    if (wv == 0) {
        const float tot = red[0][lane] + red[1][lane] + red[2][lane] + red[3][lane];
        atomicAdd(&denom[g], tot);
    }
}

// ---------------- kernel 2b: wsum[b,s] = (1/T) * sum_t E[b,t,s]/denom[b,t] ----------------
__global__ __launch_bounds__(256) void colsum_kernel(const float* __restrict__ E,
                                                     const float* __restrict__ denom,
                                                     float* __restrict__ wsum)
{
    const int b  = blockIdx.y;
    const int t0 = blockIdx.x * 4;
    const int s  = threadIdx.x;
    float a0 = 0.0f, a1 = 0.0f;
#pragma unroll
    for (int ti = 0; ti < 4; ++ti) {
        const int t = t0 + ti;
        const float rd = 1.0f / denom[b * TT + t];
        const float* __restrict__ Er = E + (size_t)(b * TT + t) * TT;
        a0 = fmaf(Er[s],       rd, a0);
        a1 = fmaf(Er[s + 256], rd, a1);
    }
    atomicAdd(&wsum[b * TT + s],       a0 * (1.0f / TT));
    atomicAdd(&wsum[b * TT + s + 256], a1 * (1.0f / TT));
}

// ---------------- kernel 3: out[b,:] = sum_s wsum[b,s] * h[b,s,:] ----------------
__global__ __launch_bounds__(512) void ctx_kernel(const float* __restrict__ h,
                                                  const float* __restrict__ wsum,
                                                  float* __restrict__ out)
{
    const int b  = blockIdx.y;
    const int s0 = blockIdx.x * 8;
    const int hd = threadIdx.x;
    float a = 0.0f;
#pragma unroll
    for (int si = 0; si < 8; ++si) {
        const int s = s0 + si;
        a = fmaf(wsum[b * TT + s], h[(size_t)(b * TT + s) * HH + hd], a);
    }
    atomicAdd(&out[b * HH + hd], a);
}

extern "C" void kernel_launch(void* const* d_in, const int* in_sizes, int n_in,
                              void* d_out, int out_size, void* d_ws, size_t ws_size,
                              hipStream_t stream)
{
    const float* h       = (const float*)d_in[0];
    const float* Wq      = (const float*)d_in[1];
    const float* Wk      = (const float*)d_in[2];
    const float* bq      = (const float*)d_in[3];
    const float* W       = (const float*)d_in[4];
    const float* b_alpha = (const float*)d_in[5];
    float* out = (float*)d_out;

    float* ws    = (float*)d_ws;
    float* EQ    = ws;                                   // 524,288 f32 (transposed quad-interleaved)
    float* EKm   = EQ + (size_t)524288;                  // 524,288 f32
    float* E     = EKm + (size_t)524288;                 // 1,048,576 f32
    float* denom = E + (size_t)1048576;                  // 2048
    float* wsum  = denom + BB * TT;                      // 2048
    float* w2    = wsum + BB * TT;                       // 256
    float* w2p   = w2 + UU;                              // 128
    float* scal  = w2p + 128;                            // 2
    float* cbq   = scal + 2;                             // 256

    // bf16 staging aliases E (E is only written by score_kernel, after qk_mfma)
    unsigned short* hbf   = (unsigned short*)E;          // 1,048,576 bf16 = 2 MB
    unsigned short* WcatT = hbf + (size_t)1048576;       // 262,144 bf16 = 512 KB

    prep_kernel  <<<513, 256, 0, stream>>>(h, Wq, Wk, bq, W, b_alpha,
                                           hbf, WcatT, cbq, w2, w2p, scal, denom, wsum, out);
    qk_mfma      <<<512, 256, 0, stream>>>(hbf, WcatT, cbq, EQ, EKm);
    score_kernel <<<dim3(64, 8, BB), 256, 0, stream>>>(EQ, EKm, w2, w2p, scal, E, denom);
    colsum_kernel<<<dim3(128, BB), 256, 0, stream>>>(E, denom, wsum);
    ctx_kernel   <<<dim3(64, BB), 512, 0, stream>>>(h, wsum, out);
}

// Round 8
// 68.844 us; speedup vs baseline: 1.4927x; 1.0850x over previous
//
#include <hip/hip_runtime.h>

#define BB 4
#define TT 512
#define HH 512
#define UU 256

// 2*log2(e): e^{2x} = 2^{c*x}
#define C2L2E 2.8853900817779268f
#define L2E   1.4426950408889634f

typedef __attribute__((ext_vector_type(8))) short bf16x8;
typedef __attribute__((ext_vector_type(4))) float f32x4;
typedef __attribute__((ext_vector_type(2))) float f32x2;

static __device__ inline unsigned short f2bf(float x) {
    union { float f; unsigned u; } v; v.f = x;
    unsigned r = v.u + 0x7fff + ((v.u >> 16) & 1);   // RNE
    return (unsigned short)(r >> 16);
}

static __device__ inline f32x2 pk_mul(f32x2 a, f32x2 b) {
    f32x2 d; asm("v_pk_mul_f32 %0, %1, %2" : "=v"(d) : "v"(a), "v"(b)); return d;
}
static __device__ inline f32x2 pk_add(f32x2 a, f32x2 b) {
    f32x2 d; asm("v_pk_add_f32 %0, %1, %2" : "=v"(d) : "v"(a), "v"(b)); return d;
}
static __device__ inline f32x2 pk_fma(f32x2 a, f32x2 b, f32x2 c) {
    f32x2 d; asm("v_pk_fma_f32 %0, %1, %2, %3" : "=v"(d) : "v"(a), "v"(b), "v"(c)); return d;
}

// ---------------- prep (513 blocks):
// blocks 0..255   : h -> bf16 (float4 -> ushort4, coalesced)
// blocks 256..511 : WcatT[n][k] = bf16(c*W{q,k}[k][n]) via LDS 32x32 tile transpose
// block 512       : w2/w2p/cbq/scal + zero denom/wsum/out
// Pairing for w2p: quad u=4q pairs (4q,4q+2) and (4q+1,4q+3):
//   w2p[2q]   = -2*(W[4q]   + W[4q+2])
//   w2p[2q+1] = -2*(W[4q+1] + W[4q+3])
__global__ __launch_bounds__(256) void prep_kernel(const float* __restrict__ h,
                                                   const float* __restrict__ Wq,
                                                   const float* __restrict__ Wk,
                                                   const float* __restrict__ bq,
                                                   const float* __restrict__ W,
                                                   const float* __restrict__ b_alpha,
                                                   unsigned short* __restrict__ hbf,
                                                   unsigned short* __restrict__ WcatT,
                                                   float* __restrict__ cbq,
                                                   float* __restrict__ w2,
                                                   float* __restrict__ w2p,
                                                   float* __restrict__ scal,
                                                   float* __restrict__ denom,
                                                   float* __restrict__ wsum,
                                                   float* __restrict__ out)
{
    const int blk = blockIdx.x;
    const int tid = threadIdx.x;

    if (blk < 256) {
        const int gid = blk * 256 + tid;                  // 65536 threads
#pragma unroll
        for (int it = 0; it < 4; ++it) {
            const int i = gid + it * 65536;               // 262144 float4 total
            const float4 v = ((const float4*)h)[i];
            ushort4 o;
            o.x = f2bf(v.x); o.y = f2bf(v.y); o.z = f2bf(v.z); o.w = f2bf(v.w);
            ((ushort4*)hbf)[i] = o;
        }
    } else if (blk < 512) {
        __shared__ unsigned short lds[32][33];
        const int tile = blk - 256;                       // 0..255
        const int tn = tile & 15;                         // n-tile
        const int tk = tile >> 4;                         // k-tile
        const int lx = tid & 31;
        const int ly = tid >> 5;                          // 0..7
        const int n = tn * 32 + lx;
#pragma unroll
        for (int kk = ly; kk < 32; kk += 8) {
            const int k = tk * 32 + kk;
            const float v = (n < 256) ? Wq[k * UU + n] : Wk[k * UU + (n - 256)];
            lds[lx][kk] = f2bf(C2L2E * v);
        }
        __syncthreads();
#pragma unroll
        for (int nn = ly; nn < 32; nn += 8) {
            WcatT[(size_t)(tn * 32 + nn) * 512 + tk * 32 + lx] = lds[nn][lx];
        }
    } else {
        __shared__ float red[256];
        const float w = W[tid];
        w2[tid] = -2.0f * w;
        red[tid] = w;
        cbq[tid] = C2L2E * bq[tid];
        if (tid < 64) {
            w2p[2 * tid]     = -2.0f * (W[4 * tid]     + W[4 * tid + 2]);
            w2p[2 * tid + 1] = -2.0f * (W[4 * tid + 1] + W[4 * tid + 3]);
        }
        __syncthreads();
        for (int off = 128; off > 0; off >>= 1) {
            if (tid < off) red[tid] += red[tid + off];
            __syncthreads();
        }
        if (tid == 0) { scal[0] = red[0]; scal[1] = b_alpha[0]; }
#pragma unroll
        for (int it = 0; it < 8; ++it) {
            const int i = tid + it * 256;                 // 2048
            denom[i] = 0.0f; wsum[i] = 0.0f; out[i] = 0.0f;
        }
    }
}

// ---------------- kernel 1: bf16 MFMA GEMM + exp2 epilogue ----------------
// M=2048, N=512, K=512.
// n<256  -> EQ = exp2(c*hq), stored TRANSPOSED quad-interleaved: EQ[(u>>2)*8192 + m*4 + (u&3)]
// n>=256 -> EK = exp2(c*hk + c*bq), stored row-major: EKm[m*256 + (n-256)]
__global__ __launch_bounds__(256) void qk_mfma(const unsigned short* __restrict__ hbf,
                                               const unsigned short* __restrict__ WcatT,
                                               const float* __restrict__ cbq,
                                               float* __restrict__ EQ,
                                               float* __restrict__ EKm)
{
    const int wave = (blockIdx.x * 256 + threadIdx.x) >> 6;   // 0..2047
    const int lane = threadIdx.x & 63;
    const int mt = wave >> 4;          // 0..127
    const int nt = wave & 15;          // 0..15
    const int m0 = mt * 16, n0 = nt * 32;
    const int lrow = lane & 15;
    const int kgrp = lane >> 4;        // 0..3

    f32x4 acc0 = {0.f, 0.f, 0.f, 0.f};
    f32x4 acc1 = {0.f, 0.f, 0.f, 0.f};
    const unsigned short* Arow = hbf   + (size_t)(m0 + lrow) * 512 + kgrp * 8;
    const unsigned short* B0   = WcatT + (size_t)(n0 + lrow) * 512 + kgrp * 8;
    const unsigned short* B1   = B0 + (size_t)16 * 512;

#pragma unroll
    for (int k0 = 0; k0 < 512; k0 += 32) {
        const bf16x8 a  = *(const bf16x8*)(Arow + k0);
        const bf16x8 b0 = *(const bf16x8*)(B0 + k0);
        const bf16x8 b1 = *(const bf16x8*)(B1 + k0);
        acc0 = __builtin_amdgcn_mfma_f32_16x16x32_bf16(a, b0, acc0, 0, 0, 0);
        acc1 = __builtin_amdgcn_mfma_f32_16x16x32_bf16(a, b1, acc1, 0, 0, 0);
    }

    const int n_0 = n0 + lrow;
    const int n_1 = n_0 + 16;
    if (nt < 8) {
#pragma unroll
        for (int r = 0; r < 4; r++) {
            const int m = m0 + kgrp * 4 + r;
            EQ[(size_t)(n_0 >> 2) * 8192 + m * 4 + (n_0 & 3)] = __builtin_amdgcn_exp2f(acc0[r]);
            EQ[(size_t)(n_1 >> 2) * 8192 + m * 4 + (n_1 & 3)] = __builtin_amdgcn_exp2f(acc1[r]);
        }
    } else {
        const float bias0 = cbq[n_0 - 256];
        const float bias1 = cbq[n_1 - 256];
#pragma unroll
        for (int r = 0; r < 4; r++) {
            const int m = m0 + kgrp * 4 + r;
            EKm[(size_t)m * 256 + (n_0 - 256)] = __builtin_amdgcn_exp2f(acc0[r] + bias0);
            EKm[(size_t)m * 256 + (n_1 - 256)] = __builtin_amdgcn_exp2f(acc1[r] + bias1);
        }
    }
}

// ---------------- kernel 2a: scores + sigmoid + exp, per-(b,t) denom ----------------
// grid (sg=64, tg=4, b=4) = 1024 blocks, 4 waves each.
// lane = t, TWO t-streams per lane (t, t+64) sharing every ek/w broadcast read.
// wave owns 2 s. e_u = EQ[t,u]*EK[s,u]. Packed quad-rational (pairs (u0,u2),(u1,u3)).
__global__ __launch_bounds__(256, 4) void score_kernel(const float* __restrict__ EQ,
                                                       const float* __restrict__ EKm,
                                                       const float* __restrict__ w2,
                                                       const float* __restrict__ w2p,
                                                       const float* __restrict__ scal,
                                                       float* __restrict__ E,
                                                       float* __restrict__ denom)
{
    const int b  = blockIdx.z;
    const int tg = blockIdx.y;          // 0..3 (128 t per block)
    const int sg = blockIdx.x;          // 0..63 (8 s per block)
    const int tid  = threadIdx.x;
    const int lane = tid & 63;
    const int wv = __builtin_amdgcn_readfirstlane((int)(tid >> 6));
    const int gA = b * TT + tg * 128 + lane;    // t-stream A
    const int gB = gA + 64;                     // t-stream B

    __shared__ float khk[2048];     // 8 rows x 256 (flat, conflict-free staging)
    __shared__ float w2l[256];
    __shared__ float w2pl[128];
    __shared__ float redA[4][64];
    __shared__ float redB[4][64];

    {   // stage: each thread writes 2 b128 at consecutive per-lane addresses
        const float* srcb = EKm + (size_t)(b * TT + sg * 8) * 256;
        *(float4*)&khk[tid * 4]        = *(const float4*)(srcb + tid * 4);
        *(float4*)&khk[tid * 4 + 1024] = *(const float4*)(srcb + tid * 4 + 1024);
        w2l[tid] = w2[tid];
        if (tid < 128) w2pl[tid] = w2p[tid];
    }
    __syncthreads();

    const float sumW    = scal[0];
    const float b_alpha = scal[1];
    const f32x2 kOne = {1.0f, 1.0f};

    const float* __restrict__ ek0b = &khk[(2 * wv + 0) * 256];
    const float* __restrict__ ek1b = &khk[(2 * wv + 1) * 256];

    float accA[2][2] = {{0.f, 0.f}, {0.f, 0.f}};
    float accB[2][2] = {{0.f, 0.f}, {0.f, 0.f}};

    for (int uc = 0; uc < UU; uc += 16) {
        f32x4 hA[4], hB[4];
#pragma unroll
        for (int q = 0; q < 4; q++) {
            const float* base = EQ + (size_t)(uc / 4 + q) * 8192;
            hA[q] = *(const f32x4*)(base + gA * 4);
            hB[q] = *(const f32x4*)(base + gB * 4);
        }
#pragma unroll
        for (int qd = 0; qd < 4; ++qd) {
            const int u = uc + 4 * qd;
            const f32x4 wv4  = *(const f32x4*)&w2l[u];
            const f32x2 w01  = __builtin_shufflevector(wv4, wv4, 0, 1);
            const f32x2 w23  = __builtin_shufflevector(wv4, wv4, 2, 3);
            const f32x2 wp   = *(const f32x2*)&w2pl[u >> 1];
            const f32x2 hA01 = __builtin_shufflevector(hA[qd], hA[qd], 0, 1);
            const f32x2 hA23 = __builtin_shufflevector(hA[qd], hA[qd], 2, 3);
            const f32x2 hB01 = __builtin_shufflevector(hB[qd], hB[qd], 0, 1);
            const f32x2 hB23 = __builtin_shufflevector(hB[qd], hB[qd], 2, 3);
#pragma unroll
            for (int si = 0; si < 2; ++si) {
                const float* __restrict__ ekb = si ? ek1b : ek0b;
                const f32x4 ekv  = *(const f32x4*)&ekb[u];
                const f32x2 ek01 = __builtin_shufflevector(ekv, ekv, 0, 1);
                const f32x2 ek23 = __builtin_shufflevector(ekv, ekv, 2, 3);
                // ---- stream A ----
                {
                    const f32x2 ev0 = pk_mul(hA01, ek01);          // (e0, e1)
                    const f32x2 ev1 = pk_mul(hA23, ek23);          // (e2, e3)
                    const f32x2 t   = pk_add(ev0, kOne);           // (1+e0, 1+e1)
                    const f32x2 d   = pk_fma(t, ev1, t);           // ((1+e0)(1+e2), (1+e1)(1+e3))
                    f32x2 n = pk_fma(w01, ev1, wp);                // wp + w0*e2 | w1*e3
                    n = pk_fma(w23, ev0, n);                       //    + w2*e0 | w3*e1
                    const float dq = d.x * d.y;
                    const float nq = fmaf(n.y, d.x, n.x * d.y);
                    const float r  = __builtin_amdgcn_rcpf(dq);
                    accA[si][qd & 1] = fmaf(nq, r, accA[si][qd & 1]);
                }
                // ---- stream B ----
                {
                    const f32x2 ev0 = pk_mul(hB01, ek01);
                    const f32x2 ev1 = pk_mul(hB23, ek23);
                    const f32x2 t   = pk_add(ev0, kOne);
                    const f32x2 d   = pk_fma(t, ev1, t);
                    f32x2 n = pk_fma(w01, ev1, wp);
                    n = pk_fma(w23, ev0, n);
                    const float dq = d.x * d.y;
                    const float nq = fmaf(n.y, d.x, n.x * d.y);
                    const float r  = __builtin_amdgcn_rcpf(dq);
                    accB[si][qd & 1] = fmaf(nq, r, accB[si][qd & 1]);
                }
            }
        }
    }

    const int s0 = sg * 8 + wv * 2;
    float EvA[2], EvB[2];
    float partA = 0.0f, partB = 0.0f;
#pragma unroll
    for (int si = 0; si < 2; ++si) {
        const float zA   = accA[si][0] + accA[si][1] + sumW + b_alpha;
        const float sgA  = __builtin_amdgcn_rcpf(1.0f + __builtin_amdgcn_exp2f(-zA * L2E));
        EvA[si] = __builtin_amdgcn_exp2f(sgA * L2E);
        partA += EvA[si];
        const float zB   = accB[si][0] + accB[si][1] + sumW + b_alpha;
        const float sgB  = __builtin_amdgcn_rcpf(1.0f + __builtin_amdgcn_exp2f(-zB * L2E));
        EvB[si] = __builtin_amdgcn_exp2f(sgB * L2E);
        partB += EvB[si];
    }

    *(float2*)(E + (size_t)gA * TT + s0) = make_float2(EvA[0], EvA[1]);
    *(float2*)(E + (size_t)gB * TT + s0) = make_float2(EvB[0], EvB[1]);

    redA[wv][lane] = partA;
    redB[wv][lane] = partB;
    __syncthreads();
    if (wv == 0) {
        const float totA = redA[0][lane] + redA[1][lane] + redA[2][lane] + redA[3][lane];
        const float totB = redB[0][lane] + redB[1][lane] + redB[2][lane] + redB[3][lane];
        atomicAdd(&denom[gA], totA);
        atomicAdd(&denom[gB], totB);
    }
}

// ---------------- kernel 2b: wsum[b,s] = (1/T) * sum_t E[b,t,s]/denom[b,t] ----------------
__global__ __launch_bounds__(256) void colsum_kernel(const float* __restrict__ E,
                                                     const float* __restrict__ denom,
                                                     float* __restrict__ wsum)
{
    const int b  = blockIdx.y;
    const int t0 = blockIdx.x * 4;
    const int s  = threadIdx.x;
    float a0 = 0.0f, a1 = 0.0f;
#pragma unroll
    for (int ti = 0; ti < 4; ++ti) {
        const int t = t0 + ti;
        const float rd = 1.0f / denom[b * TT + t];
        const float* __restrict__ Er = E + (size_t)(b * TT + t) * TT;
        a0 = fmaf(Er[s],       rd, a0);
        a1 = fmaf(Er[s + 256], rd, a1);
    }
    atomicAdd(&wsum[b * TT + s],       a0 * (1.0f / TT));
    atomicAdd(&wsum[b * TT + s + 256], a1 * (1.0f / TT));
}

// ---------------- kernel 3: out[b,:] = sum_s wsum[b,s] * h[b,s,:] ----------------
__global__ __launch_bounds__(512) void ctx_kernel(const float* __restrict__ h,
                                                  const float* __restrict__ wsum,
                                                  float* __restrict__ out)
{
    const int b  = blockIdx.y;
    const int s0 = blockIdx.x * 8;
    const int hd = threadIdx.x;
    float a = 0.0f;
#pragma unroll
    for (int si = 0; si < 8; ++si) {
        const int s = s0 + si;
        a = fmaf(wsum[b * TT + s], h[(size_t)(b * TT + s) * HH + hd], a);
    }
    atomicAdd(&out[b * HH + hd], a);
}

extern "C" void kernel_launch(void* const* d_in, const int* in_sizes, int n_in,
                              void* d_out, int out_size, void* d_ws, size_t ws_size,
                              hipStream_t stream)
{
    const float* h       = (const float*)d_in[0];
    const float* Wq      = (const float*)d_in[1];
    const float* Wk      = (const float*)d_in[2];
    const float* bq      = (const float*)d_in[3];
    const float* W       = (const float*)d_in[4];
    const float* b_alpha = (const float*)d_in[5];
    float* out = (float*)d_out;

    float* ws    = (float*)d_ws;
    float* EQ    = ws;                                   // 524,288 f32 (transposed quad-interleaved)
    float* EKm   = EQ + (size_t)524288;                  // 524,288 f32
    float* E     = EKm + (size_t)524288;                 // 1,048,576 f32
    float* denom = E + (size_t)1048576;                  // 2048
    float* wsum  = denom + BB * TT;                      // 2048
    float* w2    = wsum + BB * TT;                       // 256
    float* w2p   = w2 + UU;                              // 128
    float* scal  = w2p + 128;                            // 2
    float* cbq   = scal + 2;                             // 256

    // bf16 staging aliases E (E is only written by score_kernel, after qk_mfma)
    unsigned short* hbf   = (unsigned short*)E;          // 1,048,576 bf16 = 2 MB
    unsigned short* WcatT = hbf + (size_t)1048576;       // 262,144 bf16 = 512 KB

    prep_kernel  <<<513, 256, 0, stream>>>(h, Wq, Wk, bq, W, b_alpha,
                                           hbf, WcatT, cbq, w2, w2p, scal, denom, wsum, out);
    qk_mfma      <<<512, 256, 0, stream>>>(hbf, WcatT, cbq, EQ, EKm);
    score_kernel <<<dim3(64, 4, BB), 256, 0, stream>>>(EQ, EKm, w2, w2p, scal, E, denom);
    colsum_kernel<<<dim3(128, BB), 256, 0, stream>>>(E, denom, wsum);
    ctx_kernel   <<<dim3(64, BB), 512, 0, stream>>>(h, wsum, out);
}

// Round 9
// 67.242 us; speedup vs baseline: 1.5283x; 1.0238x over previous
//
#include <hip/hip_runtime.h>

#define BB 4
#define TT 512
#define HH 512
#define UU 256

// 2*log2(e): e^{2x} = 2^{c*x}
#define C2L2E 2.8853900817779268f
#define L2E   1.4426950408889634f

typedef __attribute__((ext_vector_type(8))) short bf16x8;
typedef __attribute__((ext_vector_type(4))) float f32x4;
typedef __attribute__((ext_vector_type(2))) float f32x2;

static __device__ inline unsigned short f2bf(float x) {
    union { float f; unsigned u; } v; v.f = x;
    unsigned r = v.u + 0x7fff + ((v.u >> 16) & 1);   // RNE
    return (unsigned short)(r >> 16);
}

static __device__ inline f32x2 pk_mul(f32x2 a, f32x2 b) {
    f32x2 d; asm("v_pk_mul_f32 %0, %1, %2" : "=v"(d) : "v"(a), "v"(b)); return d;
}
static __device__ inline f32x2 pk_add(f32x2 a, f32x2 b) {
    f32x2 d; asm("v_pk_add_f32 %0, %1, %2" : "=v"(d) : "v"(a), "v"(b)); return d;
}
static __device__ inline f32x2 pk_fma(f32x2 a, f32x2 b, f32x2 c) {
    f32x2 d; asm("v_pk_fma_f32 %0, %1, %2, %3" : "=v"(d) : "v"(a), "v"(b), "v"(c)); return d;
}

// ---------------- prep (513 blocks):
// blocks 0..255   : h -> bf16 (float4 -> ushort4, coalesced)
// blocks 256..511 : WcatT[n][k] = bf16(c*W{q,k}[k][n]) via LDS 32x32 tile transpose
// block 512       : w2/w2p/cbq/scal + zero denom/wsum/out
// w2p pairing: quad u=4q pairs (4q,4q+2) and (4q+1,4q+3):
//   w2p[2q]   = -2*(W[4q]   + W[4q+2])
//   w2p[2q+1] = -2*(W[4q+1] + W[4q+3])
__global__ __launch_bounds__(256) void prep_kernel(const float* __restrict__ h,
                                                   const float* __restrict__ Wq,
                                                   const float* __restrict__ Wk,
                                                   const float* __restrict__ bq,
                                                   const float* __restrict__ W,
                                                   const float* __restrict__ b_alpha,
                                                   unsigned short* __restrict__ hbf,
                                                   unsigned short* __restrict__ WcatT,
                                                   float* __restrict__ cbq,
                                                   float* __restrict__ w2,
                                                   float* __restrict__ w2p,
                                                   float* __restrict__ scal,
                                                   float* __restrict__ denom,
                                                   float* __restrict__ wsum,
                                                   float* __restrict__ out)
{
    const int blk = blockIdx.x;
    const int tid = threadIdx.x;

    if (blk < 256) {
        const int gid = blk * 256 + tid;                  // 65536 threads
#pragma unroll
        for (int it = 0; it < 4; ++it) {
            const int i = gid + it * 65536;               // 262144 float4 total
            const float4 v = ((const float4*)h)[i];
            ushort4 o;
            o.x = f2bf(v.x); o.y = f2bf(v.y); o.z = f2bf(v.z); o.w = f2bf(v.w);
            ((ushort4*)hbf)[i] = o;
        }
    } else if (blk < 512) {
        __shared__ unsigned short lds[32][33];
        const int tile = blk - 256;                       // 0..255
        const int tn = tile & 15;                         // n-tile
        const int tk = tile >> 4;                         // k-tile
        const int lx = tid & 31;
        const int ly = tid >> 5;                          // 0..7
        const int n = tn * 32 + lx;
#pragma unroll
        for (int kk = ly; kk < 32; kk += 8) {
            const int k = tk * 32 + kk;
            const float v = (n < 256) ? Wq[k * UU + n] : Wk[k * UU + (n - 256)];
            lds[lx][kk] = f2bf(C2L2E * v);
        }
        __syncthreads();
#pragma unroll
        for (int nn = ly; nn < 32; nn += 8) {
            WcatT[(size_t)(tn * 32 + nn) * 512 + tk * 32 + lx] = lds[nn][lx];
        }
    } else {
        __shared__ float red[256];
        const float w = W[tid];
        w2[tid] = -2.0f * w;
        red[tid] = w;
        cbq[tid] = C2L2E * bq[tid];
        if (tid < 64) {
            w2p[2 * tid]     = -2.0f * (W[4 * tid]     + W[4 * tid + 2]);
            w2p[2 * tid + 1] = -2.0f * (W[4 * tid + 1] + W[4 * tid + 3]);
        }
        __syncthreads();
        for (int off = 128; off > 0; off >>= 1) {
            if (tid < off) red[tid] += red[tid + off];
            __syncthreads();
        }
        if (tid == 0) { scal[0] = red[0]; scal[1] = b_alpha[0]; }
#pragma unroll
        for (int it = 0; it < 8; ++it) {
            const int i = tid + it * 256;                 // 2048
            denom[i] = 0.0f; wsum[i] = 0.0f; out[i] = 0.0f;
        }
    }
}

// ---------------- kernel 1: bf16 MFMA GEMM + exp2 epilogue ----------------
// M=2048, N=512, K=512.
// n<256  -> EQ = exp2(c*hq), stored TRANSPOSED quad-interleaved: EQ[(u>>2)*8192 + m*4 + (u&3)]
// n>=256 -> EK = exp2(c*hk + c*bq), stored row-major: EKm[m*256 + (n-256)]
__global__ __launch_bounds__(256) void qk_mfma(const unsigned short* __restrict__ hbf,
                                               const unsigned short* __restrict__ WcatT,
                                               const float* __restrict__ cbq,
                                               float* __restrict__ EQ,
                                               float* __restrict__ EKm)
{
    const int wave = (blockIdx.x * 256 + threadIdx.x) >> 6;   // 0..2047
    const int lane = threadIdx.x & 63;
    const int mt = wave >> 4;          // 0..127
    const int nt = wave & 15;          // 0..15
    const int m0 = mt * 16, n0 = nt * 32;
    const int lrow = lane & 15;
    const int kgrp = lane >> 4;        // 0..3

    f32x4 acc0 = {0.f, 0.f, 0.f, 0.f};
    f32x4 acc1 = {0.f, 0.f, 0.f, 0.f};
    const unsigned short* Arow = hbf   + (size_t)(m0 + lrow) * 512 + kgrp * 8;
    const unsigned short* B0   = WcatT + (size_t)(n0 + lrow) * 512 + kgrp * 8;
    const unsigned short* B1   = B0 + (size_t)16 * 512;

#pragma unroll
    for (int k0 = 0; k0 < 512; k0 += 32) {
        const bf16x8 a  = *(const bf16x8*)(Arow + k0);
        const bf16x8 b0 = *(const bf16x8*)(B0 + k0);
        const bf16x8 b1 = *(const bf16x8*)(B1 + k0);
        acc0 = __builtin_amdgcn_mfma_f32_16x16x32_bf16(a, b0, acc0, 0, 0, 0);
        acc1 = __builtin_amdgcn_mfma_f32_16x16x32_bf16(a, b1, acc1, 0, 0, 0);
    }

    const int n_0 = n0 + lrow;
    const int n_1 = n_0 + 16;
    if (nt < 8) {
#pragma unroll
        for (int r = 0; r < 4; r++) {
            const int m = m0 + kgrp * 4 + r;
            EQ[(size_t)(n_0 >> 2) * 8192 + m * 4 + (n_0 & 3)] = __builtin_amdgcn_exp2f(acc0[r]);
            EQ[(size_t)(n_1 >> 2) * 8192 + m * 4 + (n_1 & 3)] = __builtin_amdgcn_exp2f(acc1[r]);
        }
    } else {
        const float bias0 = cbq[n_0 - 256];
        const float bias1 = cbq[n_1 - 256];
#pragma unroll
        for (int r = 0; r < 4; r++) {
            const int m = m0 + kgrp * 4 + r;
            EKm[(size_t)m * 256 + (n_0 - 256)] = __builtin_amdgcn_exp2f(acc0[r] + bias0);
            EKm[(size_t)m * 256 + (n_1 - 256)] = __builtin_amdgcn_exp2f(acc1[r] + bias1);
        }
    }
}

// ---------------- kernel 2a: scores + sigmoid + exp, per-(b,t) denom ----------------
// grid (sg=64, tg=4, b=4) = 1024 blocks x 512 threads (8 waves) = 8192 waves = 8/SIMD.
// Wave wv owns u-slice [32*wv, 32*wv+32). lane = t, two t-streams (t, t+64). Block: 128 t x 8 s.
// ekp[u] = w2[partner(u)]*ek[u] staged in LDS; wp pair-sums via wave-uniform s_load.
// Partial (t,s) sums combined across the 8 u-slices through LDS; epilogue does sigmoid/exp.
__global__ __launch_bounds__(512, 8) void score_kernel(const float* __restrict__ EQ,
                                                       const float* __restrict__ EKm,
                                                       const float* __restrict__ w2,
                                                       const float* __restrict__ w2p,
                                                       const float* __restrict__ scal,
                                                       float* __restrict__ E,
                                                       float* __restrict__ denom)
{
    const int b  = blockIdx.z;
    const int tg = blockIdx.y;          // 0..3 (128 t per block)
    const int sg = blockIdx.x;          // 0..63 (8 s per block)
    const int tid  = threadIdx.x;       // 0..511
    const int lane = tid & 63;
    const int wv = __builtin_amdgcn_readfirstlane((int)(tid >> 6));  // 0..7 = u-slice owner
    const int gA = b * TT + tg * 128 + lane;    // t-stream A
    const int gB = gA + 64;                     // t-stream B

    __shared__ __align__(16) float khk [8 * 256];          // ek rows (8 s)
    __shared__ __align__(16) float khkp[8 * 256];          // ekp = ek * w2[partner]
    __shared__ __align__(16) float part[8 * 2 * 8 * 64];   // [s][st][wv][lane]
    __shared__ float dnm[128];

    {   // stage ek + ekp, coalesced; zero dnm
        const int flat = tid * 4;          // 0..2047
        const int s = flat >> 8;
        const int u = flat & 255;
        const float4 ek4 = *(const float4*)(EKm + (size_t)(b * TT + sg * 8 + s) * 256 + u);
        const float4 w4  = *(const float4*)(w2 + u);
        *(float4*)&khk[flat] = ek4;
        float4 ep;
        ep.x = ek4.x * w4.z; ep.y = ek4.y * w4.w;     // partner(u) = u^2 within quad
        ep.z = ek4.z * w4.x; ep.w = ek4.w * w4.y;
        *(float4*)&khkp[flat] = ep;
        if (tid < 128) dnm[tid] = 0.0f;
    }
    __syncthreads();

    const float* __restrict__ wpw = w2p + wv * 16;   // wave-uniform -> s_load

    float accA[8], accB[8];
#pragma unroll
    for (int s = 0; s < 8; ++s) { accA[s] = 0.0f; accB[s] = 0.0f; }

    const int uq0 = wv * 8;   // first quad of this wave's slice

    for (int sub = 0; sub < 4; ++sub) {
        const int q0 = uq0 + sub * 2;
        const f32x4 hA0 = *(const f32x4*)(EQ + (size_t)(q0    ) * 8192 + gA * 4);
        const f32x4 hA1 = *(const f32x4*)(EQ + (size_t)(q0 + 1) * 8192 + gA * 4);
        const f32x4 hB0 = *(const f32x4*)(EQ + (size_t)(q0    ) * 8192 + gB * 4);
        const f32x4 hB1 = *(const f32x4*)(EQ + (size_t)(q0 + 1) * 8192 + gB * 4);
#pragma unroll
        for (int s = 0; s < 8; ++s) {
#pragma unroll
            for (int q = 0; q < 2; ++q) {
                const int uu = (q0 + q) * 4;
                const f32x4 ekv  = *(const f32x4*)&khk [s * 256 + uu];
                const f32x4 ekpv = *(const f32x4*)&khkp[s * 256 + uu];
                const f32x2 ek01  = __builtin_shufflevector(ekv,  ekv,  0, 1);
                const f32x2 ek23  = __builtin_shufflevector(ekv,  ekv,  2, 3);
                const f32x2 ekp01 = __builtin_shufflevector(ekpv, ekpv, 0, 1);
                const f32x2 ekp23 = __builtin_shufflevector(ekpv, ekpv, 2, 3);
                const f32x2 wp2 = { wpw[(sub * 2 + q) * 2], wpw[(sub * 2 + q) * 2 + 1] };
                const f32x4 hA = q ? hA1 : hA0;
                const f32x4 hB = q ? hB1 : hB0;
                const f32x2 hA01 = __builtin_shufflevector(hA, hA, 0, 1);
                const f32x2 hA23 = __builtin_shufflevector(hA, hA, 2, 3);
                const f32x2 hB01 = __builtin_shufflevector(hB, hB, 0, 1);
                const f32x2 hB23 = __builtin_shufflevector(hB, hB, 2, 3);
                // ---- stream A ----
                {
                    const f32x2 ev0 = pk_mul(hA01, ek01);          // (e0, e1)
                    const f32x2 ev1 = pk_mul(hA23, ek23);          // (e2, e3)
                    const f32x2 t   = pk_add(ev0, (f32x2){1.0f, 1.0f});
                    const f32x2 d   = pk_fma(t, ev1, t);           // ((1+e0)(1+e2), (1+e1)(1+e3))
                    f32x2 n = pk_fma(hA01, ekp01, wp2);            // wp + w2*e0 | w3*e1
                    n = pk_fma(hA23, ekp23, n);                    //    + w0*e2 | w1*e3
                    const float dq = d.x * d.y;
                    const float nq = fmaf(n.y, d.x, n.x * d.y);
                    const float r  = __builtin_amdgcn_rcpf(dq);
                    accA[s] = fmaf(nq, r, accA[s]);
                }
                // ---- stream B ----
                {
                    const f32x2 ev0 = pk_mul(hB01, ek01);
                    const f32x2 ev1 = pk_mul(hB23, ek23);
                    const f32x2 t   = pk_add(ev0, (f32x2){1.0f, 1.0f});
                    const f32x2 d   = pk_fma(t, ev1, t);
                    f32x2 n = pk_fma(hB01, ekp01, wp2);
                    n = pk_fma(hB23, ekp23, n);
                    const float dq = d.x * d.y;
                    const float nq = fmaf(n.y, d.x, n.x * d.y);
                    const float r  = __builtin_amdgcn_rcpf(dq);
                    accB[s] = fmaf(nq, r, accB[s]);
                }
            }
        }
    }

    // write u-slice partials (conflict-free: lane-contiguous)
#pragma unroll
    for (int s = 0; s < 8; ++s) {
        part[((s * 2 + 0) * 8 + wv) * 64 + lane] = accA[s];
        part[((s * 2 + 1) * 8 + wv) * 64 + lane] = accB[s];
    }
    __syncthreads();

    // epilogue: each thread -> (t_local, 2 s): sum 8 u-slices, sigmoid, exp, E write, denom
    const float sumW    = scal[0];
    const float b_alpha = scal[1];
    const int t_local = tid & 127;
    const int sh = tid >> 7;           // 0..3 -> s pair
    const int st = t_local >> 6;       // stream
    const int li = t_local & 63;
    float Ev[2];
#pragma unroll
    for (int k = 0; k < 2; ++k) {
        const int s = sh * 2 + k;
        const float* pp = &part[(s * 2 + st) * 8 * 64 + li];
        float z = 0.0f;
#pragma unroll
        for (int w = 0; w < 8; ++w) z += pp[w * 64];
        z += sumW + b_alpha;
        const float sgm = __builtin_amdgcn_rcpf(1.0f + __builtin_amdgcn_exp2f(-z * L2E));
        Ev[k] = __builtin_amdgcn_exp2f(sgm * L2E);
    }
    const int grow = b * TT + tg * 128 + t_local;
    *(float2*)(E + (size_t)grow * TT + sg * 8 + sh * 2) = make_float2(Ev[0], Ev[1]);
    atomicAdd(&dnm[t_local], Ev[0] + Ev[1]);
    __syncthreads();
    if (tid < 128) atomicAdd(&denom[b * TT + tg * 128 + tid], dnm[tid]);
}

// ---------------- kernel 2b: wsum[b,s] = (1/T) * sum_t E[b,t,s]/denom[b,t] ----------------
__global__ __launch_bounds__(256) void colsum_kernel(const float* __restrict__ E,
                                                     const float* __restrict__ denom,
                                                     float* __restrict__ wsum)
{
    const int b  = blockIdx.y;
    const int t0 = blockIdx.x * 4;
    const int s  = threadIdx.x;
    float a0 = 0.0f, a1 = 0.0f;
#pragma unroll
    for (int ti = 0; ti < 4; ++ti) {
        const int t = t0 + ti;
        const float rd = 1.0f / denom[b * TT + t];
        const float* __restrict__ Er = E + (size_t)(b * TT + t) * TT;
        a0 = fmaf(Er[s],       rd, a0);
        a1 = fmaf(Er[s + 256], rd, a1);
    }
    atomicAdd(&wsum[b * TT + s],       a0 * (1.0f / TT));
    atomicAdd(&wsum[b * TT + s + 256], a1 * (1.0f / TT));
}

// ---------------- kernel 3: out[b,:] = sum_s wsum[b,s] * h[b,s,:] ----------------
__global__ __launch_bounds__(512) void ctx_kernel(const float* __restrict__ h,
                                                  const float* __restrict__ wsum,
                                                  float* __restrict__ out)
{
    const int b  = blockIdx.y;
    const int s0 = blockIdx.x * 8;
    const int hd = threadIdx.x;
    float a = 0.0f;
#pragma unroll
    for (int si = 0; si < 8; ++si) {
        const int s = s0 + si;
        a = fmaf(wsum[b * TT + s], h[(size_t)(b * TT + s) * HH + hd], a);
    }
    atomicAdd(&out[b * HH + hd], a);
}

extern "C" void kernel_launch(void* const* d_in, const int* in_sizes, int n_in,
                              void* d_out, int out_size, void* d_ws, size_t ws_size,
                              hipStream_t stream)
{
    const float* h       = (const float*)d_in[0];
    const float* Wq      = (const float*)d_in[1];
    const float* Wk      = (const float*)d_in[2];
    const float* bq      = (const float*)d_in[3];
    const float* W       = (const float*)d_in[4];
    const float* b_alpha = (const float*)d_in[5];
    float* out = (float*)d_out;

    float* ws    = (float*)d_ws;
    float* EQ    = ws;                                   // 524,288 f32 (transposed quad-interleaved)
    float* EKm   = EQ + (size_t)524288;                  // 524,288 f32
    float* E     = EKm + (size_t)524288;                 // 1,048,576 f32
    float* denom = E + (size_t)1048576;                  // 2048
    float* wsum  = denom + BB * TT;                      // 2048
    float* w2    = wsum + BB * TT;                       // 256
    float* w2p   = w2 + UU;                              // 128
    float* scal  = w2p + 128;                            // 2
    float* cbq   = scal + 2;                             // 256

    // bf16 staging aliases E (E is only written by score_kernel, after qk_mfma)
    unsigned short* hbf   = (unsigned short*)E;          // 1,048,576 bf16 = 2 MB
    unsigned short* WcatT = hbf + (size_t)1048576;       // 262,144 bf16 = 512 KB

    prep_kernel  <<<513, 256, 0, stream>>>(h, Wq, Wk, bq, W, b_alpha,
                                           hbf, WcatT, cbq, w2, w2p, scal, denom, wsum, out);
    qk_mfma      <<<512, 256, 0, stream>>>(hbf, WcatT, cbq, EQ, EKm);
    score_kernel <<<dim3(64, 4, BB), 512, 0, stream>>>(EQ, EKm, w2, w2p, scal, E, denom);
    colsum_kernel<<<dim3(128, BB), 256, 0, stream>>>(E, denom, wsum);
    ctx_kernel   <<<dim3(64, BB), 512, 0, stream>>>(h, wsum, out);
}